// Round 7
// baseline (1656.790 us; speedup 1.0000x reference)
//
#include <hip/hip_runtime.h>

#define TPB 256
#define NLB 64   // LSTM blocks

typedef float f32x4 __attribute__((ext_vector_type(4)));
typedef short bf16x8 __attribute__((ext_vector_type(8)));
typedef unsigned long long u64;

// ---------- helpers ----------
__device__ __forceinline__ float bf2f(unsigned short u) {
  union { unsigned int i; float f; } x; x.i = ((unsigned int)u) << 16; return x.f;
}
__device__ __forceinline__ unsigned short f2bf(float v) {
  union { float f; unsigned int i; } x; x.f = v;
  unsigned int r = (x.i + 0x7fffu + ((x.i >> 16) & 1u)) >> 16;
  return (unsigned short)r;
}
__device__ __forceinline__ float sigf(float x) { return 1.f / (1.f + __expf(-x)); }
__device__ __forceinline__ bf16x8 lda_bf8(const unsigned short* p) {
  union { uint4 u; bf16x8 v; } t; t.u = *(const uint4*)p; return t.v;
}
__device__ __forceinline__ float fma8(uint4 q, const float* w, float a) {
  union { unsigned int u; float f; } t;
  t.u = q.x << 16;         a = fmaf(w[0], t.f, a);
  t.u = q.x & 0xffff0000u; a = fmaf(w[1], t.f, a);
  t.u = q.y << 16;         a = fmaf(w[2], t.f, a);
  t.u = q.y & 0xffff0000u; a = fmaf(w[3], t.f, a);
  t.u = q.z << 16;         a = fmaf(w[4], t.f, a);
  t.u = q.z & 0xffff0000u; a = fmaf(w[5], t.f, a);
  t.u = q.w << 16;         a = fmaf(w[6], t.f, a);
  t.u = q.w & 0xffff0000u; a = fmaf(w[7], t.f, a);
  return a;
}

// ================= conv1: crop patch staged once, tap-shifted MFMA =================
// grid 4096 = 512 crops x 8 row-groups (8 out rows). out channel-last [n][64][64][16].
__global__ __launch_bounds__(TPB, 2) void conv1_tap(
    const float* __restrict__ fmap, const float* __restrict__ iseq,
    const unsigned short* __restrict__ wT,   // [16][96] bf16, k=tap*8+ic (zero pad)
    const float* __restrict__ bias,
    unsigned short* __restrict__ out) {
  __shared__ float patch[3][17][132];
  __shared__ unsigned short Bsm[16][104];
  __shared__ float bs[16];
  const int tid = threadIdx.x;
  const int n = blockIdx.x >> 3, R0 = (blockIdx.x & 7) << 3;
  const int y = (int)iseq[n * 2], x = (int)iseq[n * 2 + 1];
  const int bimg = n >> 6;

  for (int e = tid; e < 1536; e += TPB) Bsm[e / 96][e % 96] = wT[e];
  if (tid < 16) bs[tid] = bias[tid];
  for (int e = tid; e < 3 * 17 * 132; e += TPB) {
    int ic = e / 2244, rem = e % 2244, l = rem / 132, c = rem % 132;
    int i = 2 * R0 - 1 + l, j = c - 1;
    float v = 0.f;
    if ((unsigned)i < 128u && (unsigned)j < 128u) {
      int r = y + i - 64, cc = x + j - 64;
      if ((unsigned)r < 1024u && (unsigned)cc < 1024u)
        v = fmap[(((size_t)bimg * 3 + ic) << 20) + ((size_t)r << 10) + cc];
    }
    patch[ic][l][c] = v;
  }
  __syncthreads();

  const int w = tid >> 6, lane = tid & 63, fr = lane & 15, kg = lane >> 4;
  f32x4 acc[8];
#pragma unroll
  for (int m = 0; m < 8; ++m) acc[m] = {0.f, 0.f, 0.f, 0.f};

#pragma unroll
  for (int ch = 0; ch < 3; ++ch) {
    int k8 = ch * 4 + kg;
    int ki = (k8 >= 9) ? 0 : ((k8 * 11) >> 5);
    int kj = (k8 >= 9) ? 0 : (k8 - 3 * ki);
    bf16x8 bfr = lda_bf8(&Bsm[fr][k8 * 8]);
#pragma unroll
    for (int m = 0; m < 8; ++m) {
      int p = w * 128 + m * 16 + fr;
      int pr = p >> 6, pc = p & 63;
      int l = 2 * pr + ki, c = 2 * pc + kj;
      bf16x8 af = {(short)f2bf(patch[0][l][c]), (short)f2bf(patch[1][l][c]),
                   (short)f2bf(patch[2][l][c]), 0, 0, 0, 0, 0};
      acc[m] = __builtin_amdgcn_mfma_f32_16x16x32_bf16(af, bfr, acc[m], 0, 0, 0);
    }
  }
  const int rg = lane >> 4;
  float bb = bs[fr];
#pragma unroll
  for (int m = 0; m < 8; ++m) {
#pragma unroll
    for (int r = 0; r < 4; ++r) {
      int p = w * 128 + m * 16 + rg * 4 + r;
      int pr = p >> 6, pc = p & 63;
      out[(((size_t)n * 64 + R0 + pr) * 64 + pc) * 16 + fr] = f2bf(acc[m][r] + bb);
    }
  }
}

// ================= tap-shifted MFMA conv, channel-last I/O (conv2/3/4) =================
template<int CIN, int COUT_BLK, int NSPLIT, int HIN, int HOUT>
__global__ __launch_bounds__(TPB, 2) void conv_tap(
    const unsigned short* __restrict__ inb,   // bf16 [n][HIN][HIN][CIN] pre-BN
    const float* __restrict__ ss,
    const unsigned short* __restrict__ wT,    // [COUT_TOT][K] bf16, k = tap*CIN+ic
    const float* __restrict__ bias,
    unsigned short* __restrict__ out) {       // bf16 [n][HOUT][HOUT][COUT_TOT]
  constexpr int K = CIN * 9;
  constexpr int K8 = K / 8;
  constexpr int NCH = (K8 + 3) / 4;
  constexpr int KPAD = NCH * 32;
  constexpr int BS = KPAD + 8;
  constexpr int CINP = CIN + 8;
  constexpr int ICG_SH = (CIN == 16) ? 1 : (CIN == 32) ? 2 : 3;
  constexpr int TPR = HOUT / 8;
  constexpr int TILES = TPR * TPR;
  constexpr int NT = COUT_BLK / 16;
  constexpr int COUT_TOT = COUT_BLK * NSPLIT;

  __shared__ unsigned short patch[289 * CINP];
  __shared__ unsigned short Bsm[COUT_BLK * BS];
  __shared__ float ssl[CIN * 2];

  const int tid = threadIdx.x;
  const int bid = blockIdx.x;
  const int n = bid / (TILES * NSPLIT);
  const int rem = bid % (TILES * NSPLIT);
  const int tile = rem / NSPLIT;
  const int split = rem % NSPLIT;
  const int TR0 = (tile / TPR) * 8, TC0 = (tile % TPR) * 8;
  const int oc0 = split * COUT_BLK;

  for (int i = tid; i < CIN * 2; i += TPB) ssl[i] = ss[i];
  __syncthreads();

  // ---- patch stage (vectorized, channel-last) ----
  for (int e = tid; e < 289 * (CIN / 8); e += TPB) {
    int icg = e % (CIN / 8), pix = e / (CIN / 8);
    int row = pix / 17, col = pix % 17;
    int ir = 2 * TR0 - 1 + row, jc = 2 * TC0 - 1 + col;
    uint4 o = {0u, 0u, 0u, 0u};
    if ((unsigned)ir < (unsigned)HIN && (unsigned)jc < (unsigned)HIN) {
      uint4 v = *(const uint4*)&inb[(((size_t)n * HIN + ir) * HIN + jc) * CIN + icg * 8];
      unsigned int d[4] = {v.x, v.y, v.z, v.w};
      unsigned int* op = (unsigned int*)&o;
#pragma unroll
      for (int t = 0; t < 4; ++t) {
        int c = icg * 8 + 2 * t;
        float a = fmaxf(fmaf(bf2f((unsigned short)(d[t] & 0xffff)), ssl[2 * c], ssl[2 * c + 1]), 0.f);
        float b = fmaxf(fmaf(bf2f((unsigned short)(d[t] >> 16)), ssl[2 * c + 2], ssl[2 * c + 3]), 0.f);
        op[t] = (unsigned int)f2bf(a) | ((unsigned int)f2bf(b) << 16);
      }
    }
    *(uint4*)&patch[pix * CINP + icg * 8] = o;
  }
  // ---- B stage ----
  constexpr int B8 = COUT_BLK * (KPAD / 8);
  for (int e = tid; e < B8; e += TPB) {
    int oc = e / (KPAD / 8), k8i = e % (KPAD / 8);
    uint4 v = {0u, 0u, 0u, 0u};
    if (k8i * 8 < K) v = *(const uint4*)&wT[(size_t)(oc0 + oc) * K + k8i * 8];
    *(uint4*)&Bsm[oc * BS + k8i * 8] = v;
  }
  __syncthreads();

  const int wave = tid >> 6, lane = tid & 63;
  const int fr = lane & 15, kg = lane >> 4;
  const int p = wave * 16 + fr;
  const int pr = p >> 3, pc = p & 7;
  f32x4 acc[NT];
#pragma unroll
  for (int j = 0; j < NT; ++j) acc[j] = {0.f, 0.f, 0.f, 0.f};

#pragma unroll
  for (int ch = 0; ch < NCH; ++ch) {
    int k8 = ch * 4 + kg;
    int tap = k8 >> ICG_SH, icg = k8 & ((1 << ICG_SH) - 1);
    int ki = (tap * 11) >> 5;
    int kj = tap - 3 * ki;
    int addr = ((2 * pr + ki) * 17 + (2 * pc + kj)) * CINP + icg * 8;
    if (tap >= 9) addr = 0;
    bf16x8 af = lda_bf8(&patch[addr]);
#pragma unroll
    for (int j = 0; j < NT; ++j) {
      bf16x8 bfr = lda_bf8(&Bsm[(j * 16 + fr) * BS + ch * 32 + kg * 8]);
      acc[j] = __builtin_amdgcn_mfma_f32_16x16x32_bf16(af, bfr, acc[j], 0, 0, 0);
    }
  }
  const int rg = lane >> 4;
#pragma unroll
  for (int j = 0; j < NT; ++j) {
    int oc = oc0 + j * 16 + fr;
    float bb = bias[oc];
#pragma unroll
    for (int r = 0; r < 4; ++r) {
      int pp = wave * 16 + rg * 4 + r;
      int orow = TR0 + (pp >> 3), ocol = TC0 + (pp & 7);
      out[(((size_t)n * HOUT + orow) * HOUT + ocol) * COUT_TOT + oc] = f2bf(acc[j][r] + bb);
    }
  }
}

// ---------- weight transpose+cast prep (tap-major bf16) ----------
__global__ __launch_bounds__(TPB) void prep_wt(
    const float* __restrict__ w1, const float* __restrict__ w2,
    const float* __restrict__ w3, const float* __restrict__ w4,
    unsigned short* __restrict__ wt1, unsigned short* __restrict__ wt2,
    unsigned short* __restrict__ wt3, unsigned short* __restrict__ wt4) {
  int i = blockIdx.x * TPB + threadIdx.x;
  if (i < 1536) {                               // conv1: 16 x 96 (tap*8+ic, zero pad)
    int oc = i / 96, k = i % 96;
    int tap = k >> 3, ic = k & 7;
    float v = (tap < 9 && ic < 3) ? w1[(oc * 3 + ic) * 9 + tap] : 0.f;
    wt1[i] = f2bf(v);
  } else if (i < 6144) {                        // conv2: 32 x 144
    int j = i - 1536;
    int oc = j / 144, k = j % 144;
    wt2[j] = f2bf(w2[(oc * 16 + (k & 15)) * 9 + (k >> 4)]);
  } else if (i < 24576) {                       // conv3: 64 x 288
    int j = i - 6144;
    int oc = j / 288, k = j % 288;
    wt3[j] = f2bf(w3[(oc * 32 + (k & 31)) * 9 + (k >> 5)]);
  } else if (i < 98304) {                       // conv4: 128 x 576
    int j = i - 24576;
    int oc = j / 576, k = j % 576;
    wt4[j] = f2bf(w4[(oc * 64 + (k & 63)) * 9 + (k >> 6)]);
  }
}

// ---------- fw1 permute+cast: [512][128*64 c-major] -> bf16 [512][64*128 pix-major] ----------
__global__ __launch_bounds__(TPB) void permute_fw1(const float* __restrict__ in,
    unsigned short* __restrict__ out) {
  __shared__ unsigned short l[128 * 66];
  int n = blockIdx.x;
  for (int e = threadIdx.x; e < 8192; e += TPB) {
    int c = e >> 6, pix = e & 63;
    l[c * 66 + pix] = f2bf(in[(size_t)n * 8192 + e]);
  }
  __syncthreads();
  for (int e = threadIdx.x; e < 8192; e += TPB) {
    int pix = e >> 7, c = e & 127;
    out[(size_t)n * 8192 + e] = l[c * 66 + pix];
  }
}

// ---------- BN statistics, channel-last (deterministic two-stage) ----------
__global__ __launch_bounds__(TPB) void stats_cl(
    const unsigned short* __restrict__ y, float* __restrict__ part, int C, int HW) {
  int s = blockIdx.x;                     // 64 slices x 8 images
  int tid = threadIdx.x;
  int c = tid % C, g = tid / C, G = TPB / C;
  float sum = 0.f, sq = 0.f;
  for (int nn = 0; nn < 8; ++nn) {
    const unsigned short* p = y + ((size_t)(s * 8 + nn) * HW) * C + c;
    for (int pix = g; pix < HW; pix += G) {
      float v = bf2f(p[(size_t)pix * C]);
      sum += v; sq = fmaf(v, v, sq);
    }
  }
  __shared__ float rs[TPB], rq[TPB];
  rs[tid] = sum; rq[tid] = sq;
  __syncthreads();
  for (int off = TPB / 2; off >= C; off >>= 1) {
    if (tid < off) { rs[tid] += rs[tid + off]; rq[tid] += rq[tid + off]; }
    __syncthreads();
  }
  if (tid < C) { part[s * 2 * C + 2 * tid] = rs[tid]; part[s * 2 * C + 2 * tid + 1] = rq[tid]; }
}

__global__ void stats_final_cl(const float* __restrict__ part,
    const float* __restrict__ gamma, const float* __restrict__ beta,
    float* __restrict__ ss, float inv_count, int C) {
  int c = blockIdx.x;
  int t = threadIdx.x;  // 64
  float sum = part[t * 2 * C + 2 * c];
  float sq  = part[t * 2 * C + 2 * c + 1];
  for (int off = 32; off > 0; off >>= 1) {
    sum += __shfl_down(sum, off);
    sq  += __shfl_down(sq, off);
  }
  if (t == 0) {
    float mean = sum * inv_count;
    float var  = sq * inv_count - mean * mean;
    float rstd = rsqrtf(var + 1e-5f);
    float scl  = gamma[c] * rstd;
    ss[2 * c] = scl;
    ss[2 * c + 1] = beta[c] - mean * scl;
  }
}

// ---------- BN+ReLU for layer 4, channel-last (bf16 -> bf16) ----------
__global__ __launch_bounds__(TPB) void bnrelu_cl(const unsigned short* __restrict__ y,
    const float* __restrict__ ss, unsigned short* __restrict__ out) {
  int q = blockIdx.x * TPB + threadIdx.x;   // uint4 groups, total 524288
  if (q >= 524288) return;
  int c0 = (q << 3) & 127;
  uint4 v = ((const uint4*)y)[q];
  unsigned int d[4] = {v.x, v.y, v.z, v.w};
  uint4 o;
  unsigned int* op = (unsigned int*)&o;
#pragma unroll
  for (int t = 0; t < 4; ++t) {
    int c = c0 + 2 * t;
    float a = fmaxf(fmaf(bf2f((unsigned short)(d[t] & 0xffff)), ss[2 * c], ss[2 * c + 1]), 0.f);
    float b = fmaxf(fmaf(bf2f((unsigned short)(d[t] >> 16)), ss[2 * c + 2], ss[2 * c + 3]), 0.f);
    op[t] = (unsigned int)f2bf(a) | ((unsigned int)f2bf(b) << 16);
  }
  ((uint4*)out)[q] = o;
}

// ---------- fc1: bf16 MFMA GEMM, M=N=512, K=8192, relu ----------
__global__ __launch_bounds__(TPB, 2) void fc1_mfma(
    const unsigned short* __restrict__ A, const unsigned short* __restrict__ W,
    const float* __restrict__ bias, float* __restrict__ out) {
  __shared__ unsigned short As[64][64];
  __shared__ unsigned short Bs[64][64];
  const int tid = threadIdx.x;
  const int lane = tid & 63, wave = tid >> 6;
  const int wr = (wave >> 1) * 32, wc = (wave & 1) * 32;
  const int bm = blockIdx.y * 64, bn = blockIdx.x * 64;
  f32x4 acc00 = {0.f, 0.f, 0.f, 0.f}, acc01 = acc00, acc10 = acc00, acc11 = acc00;
  const int r0 = tid >> 3, c0 = tid & 7;
  const int fr = lane & 15, kg = lane >> 4;
  for (int kt = 0; kt < 128; ++kt) {
    const int kb = kt * 64;
    uint4 av0 = *(const uint4*)&A[(size_t)(bm + r0) * 8192 + kb + c0 * 8];
    uint4 av1 = *(const uint4*)&A[(size_t)(bm + r0 + 32) * 8192 + kb + c0 * 8];
    uint4 bv0 = *(const uint4*)&W[(size_t)(bn + r0) * 8192 + kb + c0 * 8];
    uint4 bv1 = *(const uint4*)&W[(size_t)(bn + r0 + 32) * 8192 + kb + c0 * 8];
    __syncthreads();
    *(uint4*)&As[r0][(c0 ^ (r0 & 7)) * 8] = av0;
    *(uint4*)&As[r0 + 32][(c0 ^ (r0 & 7)) * 8] = av1;
    *(uint4*)&Bs[r0][(c0 ^ (r0 & 7)) * 8] = bv0;
    *(uint4*)&Bs[r0 + 32][(c0 ^ (r0 & 7)) * 8] = bv1;
    __syncthreads();
#pragma unroll
    for (int ks = 0; ks < 2; ++ks) {
      int ch = ks * 4 + kg;
      int ra0 = wr + fr, ra1 = wr + 16 + fr;
      int rb0 = wc + fr, rb1 = wc + 16 + fr;
      bf16x8 a_0 = lda_bf8(&As[ra0][(ch ^ (ra0 & 7)) * 8]);
      bf16x8 a_1 = lda_bf8(&As[ra1][(ch ^ (ra1 & 7)) * 8]);
      bf16x8 b_0 = lda_bf8(&Bs[rb0][(ch ^ (rb0 & 7)) * 8]);
      bf16x8 b_1 = lda_bf8(&Bs[rb1][(ch ^ (rb1 & 7)) * 8]);
      acc00 = __builtin_amdgcn_mfma_f32_16x16x32_bf16(a_0, b_0, acc00, 0, 0, 0);
      acc01 = __builtin_amdgcn_mfma_f32_16x16x32_bf16(a_0, b_1, acc01, 0, 0, 0);
      acc10 = __builtin_amdgcn_mfma_f32_16x16x32_bf16(a_1, b_0, acc10, 0, 0, 0);
      acc11 = __builtin_amdgcn_mfma_f32_16x16x32_bf16(a_1, b_1, acc11, 0, 0, 0);
    }
  }
  const int rg = lane >> 4;
  int n0 = bn + wc + fr, n1 = n0 + 16;
  float bi0 = bias[n0], bi1 = bias[n1];
#pragma unroll
  for (int r = 0; r < 4; ++r) {
    int m0 = bm + wr + rg * 4 + r, m1 = m0 + 16;
    out[m0 * 512 + n0] = fmaxf(acc00[r] + bi0, 0.f);
    out[m0 * 512 + n1] = fmaxf(acc01[r] + bi1, 0.f);
    out[m1 * 512 + n0] = fmaxf(acc10[r] + bi0, 0.f);
    out[m1 * 512 + n1] = fmaxf(acc11[r] + bi1, 0.f);
  }
}

// ---------- small GEMM via MFMA with output stride/offset ----------
__global__ __launch_bounds__(TPB, 2) void gemm_m64(
    const float* __restrict__ A, const float* __restrict__ W,
    const float* __restrict__ bias, float* __restrict__ out,
    int N, int K, int relu, int ldo, int coff) {
  __shared__ unsigned short As[64 * 40];
  __shared__ unsigned short Bs[64 * 40];
  const int tid = threadIdx.x, lane = tid & 63, wave = tid >> 6;
  const int wr = (wave >> 1) * 32, wc = (wave & 1) * 32;
  const int bm = blockIdx.y * 64, bn = blockIdx.x * 64;
  const int fr = lane & 15, kg = lane >> 4;
  const int sr = tid >> 2, sc = (tid & 3) * 8;
  f32x4 a00 = {0.f, 0.f, 0.f, 0.f}, a01 = a00, a10 = a00, a11 = a00;
  int nch = (K + 31) >> 5;
  for (int ch = 0; ch < nch; ++ch) {
    int kb = ch * 32;
    __syncthreads();
    {
      unsigned short tmp[8];
#pragma unroll
      for (int j = 0; j < 8; ++j) {
        int k = kb + sc + j;
        tmp[j] = (k < K) ? f2bf(A[(size_t)(bm + sr) * K + k]) : (unsigned short)0;
      }
      *(uint4*)&As[sr * 40 + sc] = *(const uint4*)tmp;
      int wrow = bn + sr;
#pragma unroll
      for (int j = 0; j < 8; ++j) {
        int k = kb + sc + j;
        tmp[j] = (wrow < N && k < K) ? f2bf(W[(size_t)wrow * K + k]) : (unsigned short)0;
      }
      *(uint4*)&Bs[sr * 40 + sc] = *(const uint4*)tmp;
    }
    __syncthreads();
    bf16x8 af0 = lda_bf8(&As[(wr + fr) * 40 + kg * 8]);
    bf16x8 af1 = lda_bf8(&As[(wr + 16 + fr) * 40 + kg * 8]);
    bf16x8 bf0 = lda_bf8(&Bs[(wc + fr) * 40 + kg * 8]);
    bf16x8 bf1 = lda_bf8(&Bs[(wc + 16 + fr) * 40 + kg * 8]);
    a00 = __builtin_amdgcn_mfma_f32_16x16x32_bf16(af0, bf0, a00, 0, 0, 0);
    a01 = __builtin_amdgcn_mfma_f32_16x16x32_bf16(af0, bf1, a01, 0, 0, 0);
    a10 = __builtin_amdgcn_mfma_f32_16x16x32_bf16(af1, bf0, a10, 0, 0, 0);
    a11 = __builtin_amdgcn_mfma_f32_16x16x32_bf16(af1, bf1, a11, 0, 0, 0);
  }
  const int rg = lane >> 4;
  int n0 = bn + wc + fr, n1 = n0 + 16;
  float bi0 = (n0 < N) ? bias[n0] : 0.f;
  float bi1 = (n1 < N) ? bias[n1] : 0.f;
#pragma unroll
  for (int r = 0; r < 4; ++r) {
    int m0 = bm + wr + rg * 4 + r, m1 = m0 + 16;
    if (n0 < N) {
      float v = a00[r] + bi0; out[(size_t)m0 * ldo + coff + n0] = relu ? fmaxf(v, 0.f) : v;
      v = a10[r] + bi0;       out[(size_t)m1 * ldo + coff + n0] = relu ? fmaxf(v, 0.f) : v;
    }
    if (n1 < N) {
      float v = a01[r] + bi1; out[(size_t)m0 * ldo + coff + n1] = relu ? fmaxf(v, 0.f) : v;
      v = a11[r] + bi1;       out[(size_t)m1 * ldo + coff + n1] = relu ? fmaxf(v, 0.f) : v;
    }
  }
}

// ---------- builders ----------
__global__ __launch_bounds__(TPB) void build_enh_kernel(const float* __restrict__ cond,
    const float* __restrict__ steps, float* __restrict__ enh) {
  int i = blockIdx.x * TPB + threadIdx.x;
  if (i >= 512 * 6) return;
  int n = i / 6, k = i % 6;
  int b = n >> 6, s = n & 63;
  enh[i] = (k < 5) ? cond[b * 5 + k] : steps[b * 64 + s];
}

// ---------- LSTM: publish-h0-early, register weights, tagged exchange ----------
__global__ __launch_bounds__(TPB, 1) void lstm_kernel(
    const float* __restrict__ iseq,
    const float* __restrict__ mw, const float* __restrict__ mb,
    const float* __restrict__ w_ih0, const float* __restrict__ w_hh0,
    const float* __restrict__ b_ih0, const float* __restrict__ b_hh0,
    const float* __restrict__ w_ih1, const float* __restrict__ w_hh1,
    const float* __restrict__ b_ih1, const float* __restrict__ b_hh1,
    u64* __restrict__ h0x, u64* __restrict__ h1x,
    float* __restrict__ comb) {
  const int tid = threadIdx.x;
  const int blkid = blockIdx.x;
  const int u0 = blkid * 4;

  __shared__ float xz[64][8][16];
  __shared__ __align__(16) char reg2[26112];
  __shared__ float bias1s[16];

  float (*embc)[8][32] = (float (*)[8][32])reg2;
  float* mwmb = (float*)(reg2 + 16384);
  unsigned short (*v0s)[256] = (unsigned short (*)[256])reg2;
  unsigned short (*w1h)[256] = (unsigned short (*)[256])(reg2 + 4096);
  float (*part0)[8][16] = (float (*)[8][16])(reg2 + 8192);
  float (*part1)[8][16] = (float (*)[8][16])(reg2 + 16384);
  float (*zg0)[16] = (float (*)[16])(reg2 + 24576);
  float (*zg1)[16] = (float (*)[16])(reg2 + 25088);

  const int r = tid & 15, ks = tid >> 4;
  const int R = (r >> 2) * 256 + u0 + (r & 3);

  float w0reg[16], w1reg[32], wtmp[32];
#pragma unroll
  for (int i = 0; i < 16; ++i) w0reg[i] = w_hh0[R * 256 + ks * 16 + i];
  if (ks < 8) {
#pragma unroll
    for (int i = 0; i < 32; ++i) w1reg[i] = w_ih1[R * 256 + ks * 32 + i];
  } else {
#pragma unroll
    for (int i = 0; i < 32; ++i) w1reg[i] = w_hh1[R * 256 + (ks - 8) * 32 + i];
  }
#pragma unroll
  for (int i = 0; i < 32; ++i) wtmp[i] = w_ih0[R * 32 + i];
  const float bias0r = b_ih0[R] + b_hh0[R];
  if (tid < 16) bias1s[tid] = b_ih1[R] + b_hh1[R];
  if (tid < 96) mwmb[tid] = (tid < 64) ? mw[tid] : mb[tid - 64];
  __syncthreads();

  for (int chunk = 0; chunk < 4; ++chunk) {
    if (tid < 128) {
      int pp = tid >> 3, b = tid & 7;
      int pg = chunk * 16 + pp;
      float s0 = iseq[(b * 64 + pg) * 2 + 0];
      float s1 = iseq[(b * 64 + pg) * 2 + 1];
      for (int k = 0; k < 32; ++k)
        embc[pp][b][k] = fmaxf(fmaf(mwmb[2 * k], s0, fmaf(mwmb[2 * k + 1], s1, mwmb[64 + k])), 0.f);
    }
    __syncthreads();
    {
      int pg = chunk * 16 + ks;
      for (int b = 0; b < 8; ++b) {
        float a = bias0r;
        const float* e = &embc[ks][b][0];
#pragma unroll
        for (int k = 0; k < 32; ++k) a = fmaf(wtmp[k], e[k], a);
        xz[pg][b][r] = a;
      }
    }
    __syncthreads();
  }

  float c0 = 0.f, c1 = 0.f;
  for (int p = 0; p <= 64; ++p) {
    // ---- A0: poll h0(p-1), stage v0s ----
    if (p >= 1) {
      const unsigned tag0 = (unsigned)p;
      const u64* s0p = &h0x[(size_t)(p - 1) * 1024 + tid * 4];
      u64 a0, a1, a2, a3;
      for (;;) {
        a0 = __hip_atomic_load(&s0p[0], __ATOMIC_RELAXED, __HIP_MEMORY_SCOPE_AGENT);
        a1 = __hip_atomic_load(&s0p[1], __ATOMIC_RELAXED, __HIP_MEMORY_SCOPE_AGENT);
        a2 = __hip_atomic_load(&s0p[2], __ATOMIC_RELAXED, __HIP_MEMORY_SCOPE_AGENT);
        a3 = __hip_atomic_load(&s0p[3], __ATOMIC_RELAXED, __HIP_MEMORY_SCOPE_AGENT);
        if (((unsigned)(a0 >> 32) == tag0) & ((unsigned)(a1 >> 32) == tag0) &
            ((unsigned)(a2 >> 32) == tag0) & ((unsigned)(a3 >> 32) == tag0)) break;
        __builtin_amdgcn_s_sleep(1);
      }
#pragma unroll
      for (int i = 0; i < 4; ++i) {
        int g = tid * 4 + i;
        int bb = (g & 15) >> 1, ub = (g >> 4) * 4 + (g & 1) * 2;
        u64 va = (i == 0) ? a0 : (i == 1) ? a1 : (i == 2) ? a2 : a3;
        *(unsigned int*)&v0s[bb][ub] = (unsigned int)va;
      }
    } else {
#pragma unroll
      for (int i = 0; i < 4; ++i) ((unsigned int*)v0s)[tid * 4 + i] = 0u;
    }
    __syncthreads();

    // ---- B0: layer0 partials ----
    if (p < 64) {
#pragma unroll
      for (int b = 0; b < 8; ++b) {
        uint4 q0 = *(const uint4*)&v0s[b][ks * 16];
        uint4 q1 = *(const uint4*)&v0s[b][ks * 16 + 8];
        float a = 0.f;
        a = fma8(q0, &w0reg[0], a);
        a = fma8(q1, &w0reg[8], a);
        part0[ks][b][r] = a;
      }
    }
    __syncthreads();

    // ---- C0 (lower half) || A1 poll h1(p-2) (upper half) ----
    if (tid < 128) {
      if (p < 64) {
        int b = tid >> 4, rr = tid & 15;
        float s = xz[p][b][rr];
#pragma unroll
        for (int k2 = 0; k2 < 16; ++k2) s += part0[k2][b][rr];
        zg0[b][rr] = s;
      }
    } else {
      int t2 = tid - 128;
      if (p >= 2) {
        const unsigned tag1 = (unsigned)(p - 1);
        const u64* s1p = &h1x[(size_t)(p - 2) * 1024 + t2 * 8];
        u64 e[8];
        for (;;) {
          bool ok = true;
#pragma unroll
          for (int i = 0; i < 8; ++i) {
            e[i] = __hip_atomic_load(&s1p[i], __ATOMIC_RELAXED, __HIP_MEMORY_SCOPE_AGENT);
            ok &= ((unsigned)(e[i] >> 32) == tag1);
          }
          if (ok) break;
          __builtin_amdgcn_s_sleep(1);
        }
#pragma unroll
        for (int i = 0; i < 8; ++i) {
          int g = t2 * 8 + i;
          int bb = (g & 15) >> 1, ub = (g >> 4) * 4 + (g & 1) * 2;
          *(unsigned int*)&w1h[bb][ub] = (unsigned int)e[i];
        }
      } else {
#pragma unroll
        for (int i = 0; i < 8; ++i) ((unsigned int*)w1h)[t2 * 8 + i] = 0u;
      }
    }
    __syncthreads();

    // ---- D0: update c0, publish h0(p) EARLY ----
    if (tid < 32 && p < 64) {
      int b = tid >> 2, uu = tid & 3;
      float zi = zg0[b][uu], zf = zg0[b][4 + uu], zgv = zg0[b][8 + uu], zo = zg0[b][12 + uu];
      c0 = sigf(zf) * c0 + sigf(zi) * tanhf(zgv);
      float h = sigf(zo) * tanhf(c0);
      float hp = __shfl_xor(h, 1);
      if (!(uu & 1)) {
        unsigned int d = (unsigned int)f2bf(h) | ((unsigned int)f2bf(hp) << 16);
        u64 v = ((u64)(unsigned)(p + 1) << 32) | d;
        __hip_atomic_store(&h0x[(size_t)p * 1024 + blkid * 16 + b * 2 + (uu >> 1)], v,
                           __ATOMIC_RELAXED, __HIP_MEMORY_SCOPE_AGENT);
      }
    }

    // ---- B1: layer1 partials ----
    if (p >= 1) {
      const unsigned short* sp = (ks < 8) ? &v0s[0][ks * 32] : &w1h[0][(ks - 8) * 32];
#pragma unroll
      for (int b = 0; b < 8; ++b) {
        const uint4* qp = (const uint4*)(sp + b * 256);
        float a = 0.f;
        a = fma8(qp[0], &w1reg[0], a);
        a = fma8(qp[1], &w1reg[8], a);
        a = fma8(qp[2], &w1reg[16], a);
        a = fma8(qp[3], &w1reg[24], a);
        part1[ks][b][r] = a;
      }
    }
    __syncthreads();

    // ---- C1: reduce zg1 ----
    if (tid >= 128 && p >= 1) {
      int t2 = tid - 128, b = t2 >> 4, rr = t2 & 15;
      float s = bias1s[rr];
#pragma unroll
      for (int k2 = 0; k2 < 16; ++k2) s += part1[k2][b][rr];
      zg1[b][rr] = s;
    }
    __syncthreads();

    // ---- D1: update c1, write comb, publish h1(p-1) ----
    if (tid < 32 && p >= 1) {
      int b = tid >> 2, uu = tid & 3;
      float zi = zg1[b][uu], zf = zg1[b][4 + uu], zgv = zg1[b][8 + uu], zo = zg1[b][12 + uu];
      c1 = sigf(zf) * c1 + sigf(zi) * tanhf(zgv);
      float h = sigf(zo) * tanhf(c1);
      comb[(size_t)(b * 64 + (p - 1)) * 576 + u0 + uu] = h;
      float hp = __shfl_xor(h, 1);
      if (!(uu & 1)) {
        unsigned int d = (unsigned int)f2bf(h) | ((unsigned int)f2bf(hp) << 16);
        u64 v = ((u64)(unsigned)p << 32) | d;
        __hip_atomic_store(&h1x[(size_t)(p - 1) * 1024 + blkid * 16 + b * 2 + (uu >> 1)], v,
                           __ATOMIC_RELAXED, __HIP_MEMORY_SCOPE_AGENT);
      }
    }
  }
}

// ---------- launcher ----------
extern "C" void kernel_launch(void* const* d_in, const int* in_sizes, int n_in,
                              void* d_out, int out_size, void* d_ws, size_t ws_size,
                              hipStream_t stream) {
  const float* fmap  = (const float*)d_in[0];
  const float* cond  = (const float*)d_in[1];
  const float* iseq  = (const float*)d_in[2];
  const float* steps = (const float*)d_in[3];
  const float* cw1 = (const float*)d_in[4];  const float* cb1 = (const float*)d_in[5];
  const float* g1  = (const float*)d_in[6];  const float* be1 = (const float*)d_in[7];
  const float* cw2 = (const float*)d_in[8];  const float* cb2 = (const float*)d_in[9];
  const float* g2  = (const float*)d_in[10]; const float* be2 = (const float*)d_in[11];
  const float* cw3 = (const float*)d_in[12]; const float* cb3 = (const float*)d_in[13];
  const float* g3  = (const float*)d_in[14]; const float* be3 = (const float*)d_in[15];
  const float* cw4 = (const float*)d_in[16]; const float* cb4 = (const float*)d_in[17];
  const float* g4  = (const float*)d_in[18]; const float* be4 = (const float*)d_in[19];
  const float* fw1 = (const float*)d_in[20]; const float* fb1 = (const float*)d_in[21];
  const float* fw2 = (const float*)d_in[22]; const float* fb2 = (const float*)d_in[23];
  const float* ew1 = (const float*)d_in[24]; const float* eb1 = (const float*)d_in[25];
  const float* ew2 = (const float*)d_in[26]; const float* eb2 = (const float*)d_in[27];
  const float* mw  = (const float*)d_in[28]; const float* mb  = (const float*)d_in[29];
  const float* w_ih0 = (const float*)d_in[30]; const float* w_hh0 = (const float*)d_in[31];
  const float* b_ih0 = (const float*)d_in[32]; const float* b_hh0 = (const float*)d_in[33];
  const float* w_ih1 = (const float*)d_in[34]; const float* w_hh1 = (const float*)d_in[35];
  const float* b_ih1 = (const float*)d_in[36]; const float* b_hh1 = (const float*)d_in[37];
  const float* xw1 = (const float*)d_in[38]; const float* xb1 = (const float*)d_in[39];
  const float* xw2 = (const float*)d_in[40]; const float* xb2 = (const float*)d_in[41];
  const float* ow  = (const float*)d_in[42]; const float* ob  = (const float*)d_in[43];

  float* ws = (float*)d_ws;
  unsigned short* y1bf  = (unsigned short*)ws;                 // [512][64][64][16]
  unsigned short* y2bf  = (unsigned short*)(ws + 16777216);    // [512][32][32][32]
  unsigned short* y3bf  = (unsigned short*)(ws + 25165824);    // [512][16][16][64]
  unsigned short* y4pre = (unsigned short*)(ws + 29360128);    // [512][8][8][128]
  unsigned short* y4bn  = (unsigned short*)(ws + 31457280);
  unsigned short* fw1bf = (unsigned short*)(ws + 33554432);    // permuted
  size_t base = 35651584;
  float* part  = ws + base; base += 16384;
  float* ss1   = ws + base; base += 32;
  float* ss2   = ws + base; base += 64;
  float* ss3   = ws + base; base += 128;
  float* ss4   = ws + base; base += 256;
  float* f1    = ws + base; base += 262144;
  float* enh   = ws + base; base += 3072;
  float* ceh   = ws + base; base += 65536;
  u64*   h0x   = (u64*)(ws + base); base += 131072;
  u64*   h1x   = (u64*)(ws + base); base += 131072;
  float* comb  = ws + base; base += 294912;
  float* cx1   = ws + base; base += 65536;
  float* cx2   = ws + base; base += 32768;
  unsigned short* wt1 = (unsigned short*)(ws + base); base += 768;    // 1536 shorts
  unsigned short* wt2 = (unsigned short*)(ws + base); base += 2304;
  unsigned short* wt3 = (unsigned short*)(ws + base); base += 9216;
  unsigned short* wt4 = (unsigned short*)(ws + base); base += 36864;

  // --- prep ---
  prep_wt<<<384, TPB, 0, stream>>>(cw1, cw2, cw3, cw4, wt1, wt2, wt3, wt4);
  permute_fw1<<<512, TPB, 0, stream>>>(fw1, fw1bf);

  // --- encoder convs (channel-last bf16) ---
  conv1_tap<<<4096, TPB, 0, stream>>>(fmap, iseq, wt1, cb1, y1bf);
  stats_cl<<<64, TPB, 0, stream>>>(y1bf, part, 16, 4096);
  stats_final_cl<<<16, 64, 0, stream>>>(part, g1, be1, ss1, 1.f / 2097152.f, 16);
  conv_tap<16, 32, 1, 64, 32><<<8192, TPB, 0, stream>>>(y1bf, ss1, wt2, cb2, y2bf);
  stats_cl<<<64, TPB, 0, stream>>>(y2bf, part, 32, 1024);
  stats_final_cl<<<32, 64, 0, stream>>>(part, g2, be2, ss2, 1.f / 524288.f, 32);
  conv_tap<32, 64, 1, 32, 16><<<2048, TPB, 0, stream>>>(y2bf, ss2, wt3, cb3, y3bf);
  stats_cl<<<64, TPB, 0, stream>>>(y3bf, part, 64, 256);
  stats_final_cl<<<64, 64, 0, stream>>>(part, g3, be3, ss3, 1.f / 131072.f, 64);
  conv_tap<64, 32, 4, 16, 8><<<2048, TPB, 0, stream>>>(y3bf, ss3, wt4, cb4, y4pre);
  stats_cl<<<64, TPB, 0, stream>>>(y4pre, part, 128, 64);
  stats_final_cl<<<128, 64, 0, stream>>>(part, g4, be4, ss4, 1.f / 32768.f, 128);
  bnrelu_cl<<<2048, TPB, 0, stream>>>(y4pre, ss4, y4bn);

  // --- LSTM ---
  hipMemsetAsync(h0x, 0, 2 * 64 * 1024 * sizeof(u64), stream);
  lstm_kernel<<<NLB, TPB, 0, stream>>>(iseq, mw, mb,
                                       w_ih0, w_hh0, b_ih0, b_hh0,
                                       w_ih1, w_hh1, b_ih1, b_hh1,
                                       h0x, h1x, comb);

  // --- map-feature MLP (mapf written straight into comb cols 256..511) ---
  fc1_mfma<<<dim3(8, 8), TPB, 0, stream>>>(y4bn, fw1bf, fb1, f1);
  gemm_m64<<<dim3(4, 8), TPB, 0, stream>>>(f1, fw2, fb2, comb, 256, 512, 0, 576, 256);

  // --- condition encoder (condf -> comb cols 512..575) ---
  build_enh_kernel<<<12, TPB, 0, stream>>>(cond, steps, enh);
  gemm_m64<<<dim3(2, 8), TPB, 0, stream>>>(enh, ew1, eb1, ceh, 128, 6, 1, 128, 0);
  gemm_m64<<<dim3(1, 8), TPB, 0, stream>>>(ceh, ew2, eb2, comb, 64, 128, 0, 576, 512);

  // --- head ---
  gemm_m64<<<dim3(2, 8), TPB, 0, stream>>>(comb, xw1, xb1, cx1, 128, 576, 1, 128, 0);
  gemm_m64<<<dim3(1, 8), TPB, 0, stream>>>(cx1, xw2, xb2, cx2, 64, 128, 1, 64, 0);
  gemm_m64<<<dim3(1, 8), TPB, 0, stream>>>(cx2, ow, ob, (float*)d_out, 2, 64, 0, 2, 0);
}

// Round 8
// 673.587 us; speedup vs baseline: 2.4597x; 2.4597x over previous
//
#include <hip/hip_runtime.h>

#define TPB 256
#define NLB 64   // LSTM blocks

typedef float f32x4 __attribute__((ext_vector_type(4)));
typedef short bf16x8 __attribute__((ext_vector_type(8)));
typedef unsigned long long u64;

// ---------- helpers ----------
__device__ __forceinline__ float bf2f(unsigned short u) {
  union { unsigned int i; float f; } x; x.i = ((unsigned int)u) << 16; return x.f;
}
__device__ __forceinline__ unsigned short f2bf(float v) {
  union { float f; unsigned int i; } x; x.f = v;
  unsigned int r = (x.i + 0x7fffu + ((x.i >> 16) & 1u)) >> 16;
  return (unsigned short)r;
}
__device__ __forceinline__ float sigf(float x) { return 1.f / (1.f + __expf(-x)); }
__device__ __forceinline__ bf16x8 lda_bf8(const unsigned short* p) {
  union { uint4 u; bf16x8 v; } t; t.u = *(const uint4*)p; return t.v;
}
__device__ __forceinline__ float fma8(uint4 q, const float* w, float a) {
  union { unsigned int u; float f; } t;
  t.u = q.x << 16;         a = fmaf(w[0], t.f, a);
  t.u = q.x & 0xffff0000u; a = fmaf(w[1], t.f, a);
  t.u = q.y << 16;         a = fmaf(w[2], t.f, a);
  t.u = q.y & 0xffff0000u; a = fmaf(w[3], t.f, a);
  t.u = q.z << 16;         a = fmaf(w[4], t.f, a);
  t.u = q.z & 0xffff0000u; a = fmaf(w[5], t.f, a);
  t.u = q.w << 16;         a = fmaf(w[6], t.f, a);
  t.u = q.w & 0xffff0000u; a = fmaf(w[7], t.f, a);
  return a;
}

// ================= conv1: crop patch staged once, tap-shifted MFMA =================
// grid 4096 = 512 crops x 8 row-groups (8 out rows). out channel-last [n][64][64][16].
__global__ __launch_bounds__(TPB, 2) void conv1_tap(
    const float* __restrict__ fmap, const float* __restrict__ iseq,
    const unsigned short* __restrict__ wT,   // [16][96] bf16, k=tap*8+ic (zero pad)
    const float* __restrict__ bias,
    unsigned short* __restrict__ out) {
  __shared__ float patch[3][17][132];
  __shared__ unsigned short Bsm[16][104];
  __shared__ float bs[16];
  const int tid = threadIdx.x;
  const int n = blockIdx.x >> 3, R0 = (blockIdx.x & 7) << 3;
  const int y = (int)iseq[n * 2], x = (int)iseq[n * 2 + 1];
  const int bimg = n >> 6;

  for (int e = tid; e < 1536; e += TPB) Bsm[e / 96][e % 96] = wT[e];
  if (tid < 16) bs[tid] = bias[tid];
  for (int e = tid; e < 3 * 17 * 132; e += TPB) {
    int ic = e / 2244, rem = e % 2244, l = rem / 132, c = rem % 132;
    int i = 2 * R0 - 1 + l, j = c - 1;
    float v = 0.f;
    if ((unsigned)i < 128u && (unsigned)j < 128u) {
      int r = y + i - 64, cc = x + j - 64;
      if ((unsigned)r < 1024u && (unsigned)cc < 1024u)
        v = fmap[(((size_t)bimg * 3 + ic) << 20) + ((size_t)r << 10) + cc];
    }
    patch[ic][l][c] = v;
  }
  __syncthreads();

  const int w = tid >> 6, lane = tid & 63, fr = lane & 15, kg = lane >> 4;
  f32x4 acc[8];
#pragma unroll
  for (int m = 0; m < 8; ++m) acc[m] = {0.f, 0.f, 0.f, 0.f};

#pragma unroll
  for (int ch = 0; ch < 3; ++ch) {
    int k8 = ch * 4 + kg;
    int ki = (k8 >= 9) ? 0 : ((k8 * 11) >> 5);
    int kj = (k8 >= 9) ? 0 : (k8 - 3 * ki);
    bf16x8 bfr = lda_bf8(&Bsm[fr][k8 * 8]);
#pragma unroll
    for (int m = 0; m < 8; ++m) {
      int p = w * 128 + m * 16 + fr;
      int pr = p >> 6, pc = p & 63;
      int l = 2 * pr + ki, c = 2 * pc + kj;
      bf16x8 af = {(short)f2bf(patch[0][l][c]), (short)f2bf(patch[1][l][c]),
                   (short)f2bf(patch[2][l][c]), 0, 0, 0, 0, 0};
      acc[m] = __builtin_amdgcn_mfma_f32_16x16x32_bf16(af, bfr, acc[m], 0, 0, 0);
    }
  }
  const int rg = lane >> 4;
  float bb = bs[fr];
#pragma unroll
  for (int m = 0; m < 8; ++m) {
#pragma unroll
    for (int r = 0; r < 4; ++r) {
      int p = w * 128 + m * 16 + rg * 4 + r;
      int pr = p >> 6, pc = p & 63;
      out[(((size_t)n * 64 + R0 + pr) * 64 + pc) * 16 + fr] = f2bf(acc[m][r] + bb);
    }
  }
}

// ================= tap-shifted MFMA conv, channel-last I/O (conv2/3/4) =================
template<int CIN, int COUT_BLK, int NSPLIT, int HIN, int HOUT>
__global__ __launch_bounds__(TPB, 2) void conv_tap(
    const unsigned short* __restrict__ inb,   // bf16 [n][HIN][HIN][CIN] pre-BN
    const float* __restrict__ ss,
    const unsigned short* __restrict__ wT,    // [COUT_TOT][K] bf16, k = tap*CIN+ic
    const float* __restrict__ bias,
    unsigned short* __restrict__ out) {       // bf16 [n][HOUT][HOUT][COUT_TOT]
  constexpr int K = CIN * 9;
  constexpr int K8 = K / 8;
  constexpr int NCH = (K8 + 3) / 4;
  constexpr int KPAD = NCH * 32;
  constexpr int BS = KPAD + 8;
  constexpr int CINP = CIN + 8;
  constexpr int ICG_SH = (CIN == 16) ? 1 : (CIN == 32) ? 2 : 3;
  constexpr int TPR = HOUT / 8;
  constexpr int TILES = TPR * TPR;
  constexpr int NT = COUT_BLK / 16;
  constexpr int COUT_TOT = COUT_BLK * NSPLIT;

  __shared__ unsigned short patch[289 * CINP];
  __shared__ unsigned short Bsm[COUT_BLK * BS];
  __shared__ float ssl[CIN * 2];

  const int tid = threadIdx.x;
  const int bid = blockIdx.x;
  const int n = bid / (TILES * NSPLIT);
  const int rem = bid % (TILES * NSPLIT);
  const int tile = rem / NSPLIT;
  const int split = rem % NSPLIT;
  const int TR0 = (tile / TPR) * 8, TC0 = (tile % TPR) * 8;
  const int oc0 = split * COUT_BLK;

  for (int i = tid; i < CIN * 2; i += TPB) ssl[i] = ss[i];
  __syncthreads();

  // ---- patch stage (vectorized, channel-last) ----
  for (int e = tid; e < 289 * (CIN / 8); e += TPB) {
    int icg = e % (CIN / 8), pix = e / (CIN / 8);
    int row = pix / 17, col = pix % 17;
    int ir = 2 * TR0 - 1 + row, jc = 2 * TC0 - 1 + col;
    uint4 o = {0u, 0u, 0u, 0u};
    if ((unsigned)ir < (unsigned)HIN && (unsigned)jc < (unsigned)HIN) {
      uint4 v = *(const uint4*)&inb[(((size_t)n * HIN + ir) * HIN + jc) * CIN + icg * 8];
      unsigned int d[4] = {v.x, v.y, v.z, v.w};
      unsigned int* op = (unsigned int*)&o;
#pragma unroll
      for (int t = 0; t < 4; ++t) {
        int c = icg * 8 + 2 * t;
        float a = fmaxf(fmaf(bf2f((unsigned short)(d[t] & 0xffff)), ssl[2 * c], ssl[2 * c + 1]), 0.f);
        float b = fmaxf(fmaf(bf2f((unsigned short)(d[t] >> 16)), ssl[2 * c + 2], ssl[2 * c + 3]), 0.f);
        op[t] = (unsigned int)f2bf(a) | ((unsigned int)f2bf(b) << 16);
      }
    }
    *(uint4*)&patch[pix * CINP + icg * 8] = o;
  }
  // ---- B stage ----
  constexpr int B8 = COUT_BLK * (KPAD / 8);
  for (int e = tid; e < B8; e += TPB) {
    int oc = e / (KPAD / 8), k8i = e % (KPAD / 8);
    uint4 v = {0u, 0u, 0u, 0u};
    if (k8i * 8 < K) v = *(const uint4*)&wT[(size_t)(oc0 + oc) * K + k8i * 8];
    *(uint4*)&Bsm[oc * BS + k8i * 8] = v;
  }
  __syncthreads();

  const int wave = tid >> 6, lane = tid & 63;
  const int fr = lane & 15, kg = lane >> 4;
  const int p = wave * 16 + fr;
  const int pr = p >> 3, pc = p & 7;
  f32x4 acc[NT];
#pragma unroll
  for (int j = 0; j < NT; ++j) acc[j] = {0.f, 0.f, 0.f, 0.f};

#pragma unroll
  for (int ch = 0; ch < NCH; ++ch) {
    int k8 = ch * 4 + kg;
    int tap = k8 >> ICG_SH, icg = k8 & ((1 << ICG_SH) - 1);
    int ki = (tap * 11) >> 5;
    int kj = tap - 3 * ki;
    int addr = ((2 * pr + ki) * 17 + (2 * pc + kj)) * CINP + icg * 8;
    if (tap >= 9) addr = 0;
    bf16x8 af = lda_bf8(&patch[addr]);
#pragma unroll
    for (int j = 0; j < NT; ++j) {
      bf16x8 bfr = lda_bf8(&Bsm[(j * 16 + fr) * BS + ch * 32 + kg * 8]);
      acc[j] = __builtin_amdgcn_mfma_f32_16x16x32_bf16(af, bfr, acc[j], 0, 0, 0);
    }
  }
  const int rg = lane >> 4;
#pragma unroll
  for (int j = 0; j < NT; ++j) {
    int oc = oc0 + j * 16 + fr;
    float bb = bias[oc];
#pragma unroll
    for (int r = 0; r < 4; ++r) {
      int pp = wave * 16 + rg * 4 + r;
      int orow = TR0 + (pp >> 3), ocol = TC0 + (pp & 7);
      out[(((size_t)n * HOUT + orow) * HOUT + ocol) * COUT_TOT + oc] = f2bf(acc[j][r] + bb);
    }
  }
}

// ---------- weight transpose+cast prep (tap-major bf16) ----------
__global__ __launch_bounds__(TPB) void prep_wt(
    const float* __restrict__ w1, const float* __restrict__ w2,
    const float* __restrict__ w3, const float* __restrict__ w4,
    unsigned short* __restrict__ wt1, unsigned short* __restrict__ wt2,
    unsigned short* __restrict__ wt3, unsigned short* __restrict__ wt4) {
  int i = blockIdx.x * TPB + threadIdx.x;
  if (i < 1536) {                               // conv1: 16 x 96 (tap*8+ic, zero pad)
    int oc = i / 96, k = i % 96;
    int tap = k >> 3, ic = k & 7;
    float v = (tap < 9 && ic < 3) ? w1[(oc * 3 + ic) * 9 + tap] : 0.f;
    wt1[i] = f2bf(v);
  } else if (i < 6144) {                        // conv2: 32 x 144
    int j = i - 1536;
    int oc = j / 144, k = j % 144;
    wt2[j] = f2bf(w2[(oc * 16 + (k & 15)) * 9 + (k >> 4)]);
  } else if (i < 24576) {                       // conv3: 64 x 288
    int j = i - 6144;
    int oc = j / 288, k = j % 288;
    wt3[j] = f2bf(w3[(oc * 32 + (k & 31)) * 9 + (k >> 5)]);
  } else if (i < 98304) {                       // conv4: 128 x 576
    int j = i - 24576;
    int oc = j / 576, k = j % 576;
    wt4[j] = f2bf(w4[(oc * 64 + (k & 63)) * 9 + (k >> 6)]);
  }
}

// ---------- fw1 permute+cast: [512][128*64 c-major] -> bf16 [512][64*128 pix-major] ----------
__global__ __launch_bounds__(TPB) void permute_fw1(const float* __restrict__ in,
    unsigned short* __restrict__ out) {
  __shared__ unsigned short l[128 * 66];
  int n = blockIdx.x;
  for (int e = threadIdx.x; e < 8192; e += TPB) {
    int c = e >> 6, pix = e & 63;
    l[c * 66 + pix] = f2bf(in[(size_t)n * 8192 + e]);
  }
  __syncthreads();
  for (int e = threadIdx.x; e < 8192; e += TPB) {
    int pix = e >> 7, c = e & 127;
    out[(size_t)n * 8192 + e] = l[c * 66 + pix];
  }
}

// ---------- BN statistics, channel-last, vectorized (deterministic two-stage) ----------
// grid 512, uint4 grid-stride. Each thread owns channel-octet (tid % NQ), NQ = C/8.
#define STAT_NB 512
__global__ __launch_bounds__(TPB) void stats_cl2(
    const unsigned short* __restrict__ y, float* __restrict__ part,
    int C, int total_u4) {
  const int tid = threadIdx.x, bid = blockIdx.x;
  const int NQ = C >> 3;
  float s[8], q[8];
#pragma unroll
  for (int j = 0; j < 8; ++j) { s[j] = 0.f; q[j] = 0.f; }
  for (int i = bid * TPB + tid; i < total_u4; i += STAT_NB * TPB) {
    uint4 v = ((const uint4*)y)[i];
    unsigned int d[4] = {v.x, v.y, v.z, v.w};
#pragma unroll
    for (int t = 0; t < 4; ++t) {
      float a = bf2f((unsigned short)(d[t] & 0xffff));
      float b = bf2f((unsigned short)(d[t] >> 16));
      s[2 * t] += a;     q[2 * t] = fmaf(a, a, q[2 * t]);
      s[2 * t + 1] += b; q[2 * t + 1] = fmaf(b, b, q[2 * t + 1]);
    }
  }
  __shared__ float rs[TPB][8];
  __shared__ float rq[TPB][8];
#pragma unroll
  for (int j = 0; j < 8; ++j) { rs[tid][j] = s[j]; rq[tid][j] = q[j]; }
  __syncthreads();
  for (int off = TPB / 2; off >= NQ; off >>= 1) {
    if (tid < off) {
#pragma unroll
      for (int j = 0; j < 8; ++j) { rs[tid][j] += rs[tid + off][j]; rq[tid][j] += rq[tid + off][j]; }
    }
    __syncthreads();
  }
  if (tid < NQ) {
#pragma unroll
    for (int j = 0; j < 8; ++j) {
      int c = tid * 8 + j;
      part[(size_t)bid * 2 * C + 2 * c] = rs[tid][j];
      part[(size_t)bid * 2 * C + 2 * c + 1] = rq[tid][j];
    }
  }
}

__global__ __launch_bounds__(TPB) void stats_final2(const float* __restrict__ part,
    const float* __restrict__ gamma, const float* __restrict__ beta,
    float* __restrict__ ss, float inv_count, int C) {
  int c = blockIdx.x, tid = threadIdx.x;
  float sum = part[(size_t)tid * 2 * C + 2 * c] + part[(size_t)(tid + 256) * 2 * C + 2 * c];
  float sq  = part[(size_t)tid * 2 * C + 2 * c + 1] + part[(size_t)(tid + 256) * 2 * C + 2 * c + 1];
  __shared__ float rs[TPB], rq[TPB];
  rs[tid] = sum; rq[tid] = sq;
  __syncthreads();
  for (int off = TPB / 2; off > 0; off >>= 1) {
    if (tid < off) { rs[tid] += rs[tid + off]; rq[tid] += rq[tid + off]; }
    __syncthreads();
  }
  if (tid == 0) {
    float mean = rs[0] * inv_count;
    float var  = rq[0] * inv_count - mean * mean;
    float rstd = rsqrtf(var + 1e-5f);
    float scl  = gamma[c] * rstd;
    ss[2 * c] = scl;
    ss[2 * c + 1] = beta[c] - mean * scl;
  }
}

// ---------- BN+ReLU for layer 4, channel-last (bf16 -> bf16) ----------
__global__ __launch_bounds__(TPB) void bnrelu_cl(const unsigned short* __restrict__ y,
    const float* __restrict__ ss, unsigned short* __restrict__ out) {
  int q = blockIdx.x * TPB + threadIdx.x;   // uint4 groups, total 524288
  if (q >= 524288) return;
  int c0 = (q << 3) & 127;
  uint4 v = ((const uint4*)y)[q];
  unsigned int d[4] = {v.x, v.y, v.z, v.w};
  uint4 o;
  unsigned int* op = (unsigned int*)&o;
#pragma unroll
  for (int t = 0; t < 4; ++t) {
    int c = c0 + 2 * t;
    float a = fmaxf(fmaf(bf2f((unsigned short)(d[t] & 0xffff)), ss[2 * c], ss[2 * c + 1]), 0.f);
    float b = fmaxf(fmaf(bf2f((unsigned short)(d[t] >> 16)), ss[2 * c + 2], ss[2 * c + 3]), 0.f);
    op[t] = (unsigned int)f2bf(a) | ((unsigned int)f2bf(b) << 16);
  }
  ((uint4*)out)[q] = o;
}

// ---------- fc1: bf16 MFMA GEMM, M=N=512, K=8192, relu ----------
__global__ __launch_bounds__(TPB, 2) void fc1_mfma(
    const unsigned short* __restrict__ A, const unsigned short* __restrict__ W,
    const float* __restrict__ bias, float* __restrict__ out) {
  __shared__ unsigned short As[64][64];
  __shared__ unsigned short Bs[64][64];
  const int tid = threadIdx.x;
  const int lane = tid & 63, wave = tid >> 6;
  const int wr = (wave >> 1) * 32, wc = (wave & 1) * 32;
  const int bm = blockIdx.y * 64, bn = blockIdx.x * 64;
  f32x4 acc00 = {0.f, 0.f, 0.f, 0.f}, acc01 = acc00, acc10 = acc00, acc11 = acc00;
  const int r0 = tid >> 3, c0 = tid & 7;
  const int fr = lane & 15, kg = lane >> 4;
  for (int kt = 0; kt < 128; ++kt) {
    const int kb = kt * 64;
    uint4 av0 = *(const uint4*)&A[(size_t)(bm + r0) * 8192 + kb + c0 * 8];
    uint4 av1 = *(const uint4*)&A[(size_t)(bm + r0 + 32) * 8192 + kb + c0 * 8];
    uint4 bv0 = *(const uint4*)&W[(size_t)(bn + r0) * 8192 + kb + c0 * 8];
    uint4 bv1 = *(const uint4*)&W[(size_t)(bn + r0 + 32) * 8192 + kb + c0 * 8];
    __syncthreads();
    *(uint4*)&As[r0][(c0 ^ (r0 & 7)) * 8] = av0;
    *(uint4*)&As[r0 + 32][(c0 ^ (r0 & 7)) * 8] = av1;
    *(uint4*)&Bs[r0][(c0 ^ (r0 & 7)) * 8] = bv0;
    *(uint4*)&Bs[r0 + 32][(c0 ^ (r0 & 7)) * 8] = bv1;
    __syncthreads();
#pragma unroll
    for (int ks = 0; ks < 2; ++ks) {
      int ch = ks * 4 + kg;
      int ra0 = wr + fr, ra1 = wr + 16 + fr;
      int rb0 = wc + fr, rb1 = wc + 16 + fr;
      bf16x8 a_0 = lda_bf8(&As[ra0][(ch ^ (ra0 & 7)) * 8]);
      bf16x8 a_1 = lda_bf8(&As[ra1][(ch ^ (ra1 & 7)) * 8]);
      bf16x8 b_0 = lda_bf8(&Bs[rb0][(ch ^ (rb0 & 7)) * 8]);
      bf16x8 b_1 = lda_bf8(&Bs[rb1][(ch ^ (rb1 & 7)) * 8]);
      acc00 = __builtin_amdgcn_mfma_f32_16x16x32_bf16(a_0, b_0, acc00, 0, 0, 0);
      acc01 = __builtin_amdgcn_mfma_f32_16x16x32_bf16(a_0, b_1, acc01, 0, 0, 0);
      acc10 = __builtin_amdgcn_mfma_f32_16x16x32_bf16(a_1, b_0, acc10, 0, 0, 0);
      acc11 = __builtin_amdgcn_mfma_f32_16x16x32_bf16(a_1, b_1, acc11, 0, 0, 0);
    }
  }
  const int rg = lane >> 4;
  int n0 = bn + wc + fr, n1 = n0 + 16;
  float bi0 = bias[n0], bi1 = bias[n1];
#pragma unroll
  for (int r = 0; r < 4; ++r) {
    int m0 = bm + wr + rg * 4 + r, m1 = m0 + 16;
    out[m0 * 512 + n0] = fmaxf(acc00[r] + bi0, 0.f);
    out[m0 * 512 + n1] = fmaxf(acc01[r] + bi1, 0.f);
    out[m1 * 512 + n0] = fmaxf(acc10[r] + bi0, 0.f);
    out[m1 * 512 + n1] = fmaxf(acc11[r] + bi1, 0.f);
  }
}

// ---------- small GEMM via MFMA with output stride/offset ----------
__global__ __launch_bounds__(TPB, 2) void gemm_m64(
    const float* __restrict__ A, const float* __restrict__ W,
    const float* __restrict__ bias, float* __restrict__ out,
    int N, int K, int relu, int ldo, int coff) {
  __shared__ unsigned short As[64 * 40];
  __shared__ unsigned short Bs[64 * 40];
  const int tid = threadIdx.x, lane = tid & 63, wave = tid >> 6;
  const int wr = (wave >> 1) * 32, wc = (wave & 1) * 32;
  const int bm = blockIdx.y * 64, bn = blockIdx.x * 64;
  const int fr = lane & 15, kg = lane >> 4;
  const int sr = tid >> 2, sc = (tid & 3) * 8;
  f32x4 a00 = {0.f, 0.f, 0.f, 0.f}, a01 = a00, a10 = a00, a11 = a00;
  int nch = (K + 31) >> 5;
  for (int ch = 0; ch < nch; ++ch) {
    int kb = ch * 32;
    __syncthreads();
    {
      unsigned short tmp[8];
#pragma unroll
      for (int j = 0; j < 8; ++j) {
        int k = kb + sc + j;
        tmp[j] = (k < K) ? f2bf(A[(size_t)(bm + sr) * K + k]) : (unsigned short)0;
      }
      *(uint4*)&As[sr * 40 + sc] = *(const uint4*)tmp;
      int wrow = bn + sr;
#pragma unroll
      for (int j = 0; j < 8; ++j) {
        int k = kb + sc + j;
        tmp[j] = (wrow < N && k < K) ? f2bf(W[(size_t)wrow * K + k]) : (unsigned short)0;
      }
      *(uint4*)&Bs[sr * 40 + sc] = *(const uint4*)tmp;
    }
    __syncthreads();
    bf16x8 af0 = lda_bf8(&As[(wr + fr) * 40 + kg * 8]);
    bf16x8 af1 = lda_bf8(&As[(wr + 16 + fr) * 40 + kg * 8]);
    bf16x8 bf0 = lda_bf8(&Bs[(wc + fr) * 40 + kg * 8]);
    bf16x8 bf1 = lda_bf8(&Bs[(wc + 16 + fr) * 40 + kg * 8]);
    a00 = __builtin_amdgcn_mfma_f32_16x16x32_bf16(af0, bf0, a00, 0, 0, 0);
    a01 = __builtin_amdgcn_mfma_f32_16x16x32_bf16(af0, bf1, a01, 0, 0, 0);
    a10 = __builtin_amdgcn_mfma_f32_16x16x32_bf16(af1, bf0, a10, 0, 0, 0);
    a11 = __builtin_amdgcn_mfma_f32_16x16x32_bf16(af1, bf1, a11, 0, 0, 0);
  }
  const int rg = lane >> 4;
  int n0 = bn + wc + fr, n1 = n0 + 16;
  float bi0 = (n0 < N) ? bias[n0] : 0.f;
  float bi1 = (n1 < N) ? bias[n1] : 0.f;
#pragma unroll
  for (int r = 0; r < 4; ++r) {
    int m0 = bm + wr + rg * 4 + r, m1 = m0 + 16;
    if (n0 < N) {
      float v = a00[r] + bi0; out[(size_t)m0 * ldo + coff + n0] = relu ? fmaxf(v, 0.f) : v;
      v = a10[r] + bi0;       out[(size_t)m1 * ldo + coff + n0] = relu ? fmaxf(v, 0.f) : v;
    }
    if (n1 < N) {
      float v = a01[r] + bi1; out[(size_t)m0 * ldo + coff + n1] = relu ? fmaxf(v, 0.f) : v;
      v = a11[r] + bi1;       out[(size_t)m1 * ldo + coff + n1] = relu ? fmaxf(v, 0.f) : v;
    }
  }
}

// ---------- builders ----------
__global__ __launch_bounds__(TPB) void build_enh_kernel(const float* __restrict__ cond,
    const float* __restrict__ steps, float* __restrict__ enh) {
  int i = blockIdx.x * TPB + threadIdx.x;
  if (i >= 512 * 6) return;
  int n = i / 6, k = i % 6;
  int b = n >> 6, s = n & 63;
  enh[i] = (k < 5) ? cond[b * 5 + k] : steps[b * 64 + s];
}

// ---------- LSTM: publish-h0-early, register weights, tagged exchange ----------
__global__ __launch_bounds__(TPB, 1) void lstm_kernel(
    const float* __restrict__ iseq,
    const float* __restrict__ mw, const float* __restrict__ mb,
    const float* __restrict__ w_ih0, const float* __restrict__ w_hh0,
    const float* __restrict__ b_ih0, const float* __restrict__ b_hh0,
    const float* __restrict__ w_ih1, const float* __restrict__ w_hh1,
    const float* __restrict__ b_ih1, const float* __restrict__ b_hh1,
    u64* __restrict__ h0x, u64* __restrict__ h1x,
    float* __restrict__ comb) {
  const int tid = threadIdx.x;
  const int blkid = blockIdx.x;
  const int u0 = blkid * 4;

  __shared__ float xz[64][8][16];
  __shared__ __align__(16) char reg2[26112];
  __shared__ float bias1s[16];

  float (*embc)[8][32] = (float (*)[8][32])reg2;
  float* mwmb = (float*)(reg2 + 16384);
  unsigned short (*v0s)[256] = (unsigned short (*)[256])reg2;
  unsigned short (*w1h)[256] = (unsigned short (*)[256])(reg2 + 4096);
  float (*part0)[8][16] = (float (*)[8][16])(reg2 + 8192);
  float (*part1)[8][16] = (float (*)[8][16])(reg2 + 16384);
  float (*zg0)[16] = (float (*)[16])(reg2 + 24576);
  float (*zg1)[16] = (float (*)[16])(reg2 + 25088);

  const int r = tid & 15, ks = tid >> 4;
  const int R = (r >> 2) * 256 + u0 + (r & 3);

  float w0reg[16], w1reg[32], wtmp[32];
#pragma unroll
  for (int i = 0; i < 16; ++i) w0reg[i] = w_hh0[R * 256 + ks * 16 + i];
  if (ks < 8) {
#pragma unroll
    for (int i = 0; i < 32; ++i) w1reg[i] = w_ih1[R * 256 + ks * 32 + i];
  } else {
#pragma unroll
    for (int i = 0; i < 32; ++i) w1reg[i] = w_hh1[R * 256 + (ks - 8) * 32 + i];
  }
#pragma unroll
  for (int i = 0; i < 32; ++i) wtmp[i] = w_ih0[R * 32 + i];
  const float bias0r = b_ih0[R] + b_hh0[R];
  if (tid < 16) bias1s[tid] = b_ih1[R] + b_hh1[R];
  if (tid < 96) mwmb[tid] = (tid < 64) ? mw[tid] : mb[tid - 64];
  __syncthreads();

  for (int chunk = 0; chunk < 4; ++chunk) {
    if (tid < 128) {
      int pp = tid >> 3, b = tid & 7;
      int pg = chunk * 16 + pp;
      float s0 = iseq[(b * 64 + pg) * 2 + 0];
      float s1 = iseq[(b * 64 + pg) * 2 + 1];
      for (int k = 0; k < 32; ++k)
        embc[pp][b][k] = fmaxf(fmaf(mwmb[2 * k], s0, fmaf(mwmb[2 * k + 1], s1, mwmb[64 + k])), 0.f);
    }
    __syncthreads();
    {
      int pg = chunk * 16 + ks;
      for (int b = 0; b < 8; ++b) {
        float a = bias0r;
        const float* e = &embc[ks][b][0];
#pragma unroll
        for (int k = 0; k < 32; ++k) a = fmaf(wtmp[k], e[k], a);
        xz[pg][b][r] = a;
      }
    }
    __syncthreads();
  }

  float c0 = 0.f, c1 = 0.f;
  for (int p = 0; p <= 64; ++p) {
    // ---- A0: poll h0(p-1), stage v0s ----
    if (p >= 1) {
      const unsigned tag0 = (unsigned)p;
      const u64* s0p = &h0x[(size_t)(p - 1) * 1024 + tid * 4];
      u64 a0, a1, a2, a3;
      for (;;) {
        a0 = __hip_atomic_load(&s0p[0], __ATOMIC_RELAXED, __HIP_MEMORY_SCOPE_AGENT);
        a1 = __hip_atomic_load(&s0p[1], __ATOMIC_RELAXED, __HIP_MEMORY_SCOPE_AGENT);
        a2 = __hip_atomic_load(&s0p[2], __ATOMIC_RELAXED, __HIP_MEMORY_SCOPE_AGENT);
        a3 = __hip_atomic_load(&s0p[3], __ATOMIC_RELAXED, __HIP_MEMORY_SCOPE_AGENT);
        if (((unsigned)(a0 >> 32) == tag0) & ((unsigned)(a1 >> 32) == tag0) &
            ((unsigned)(a2 >> 32) == tag0) & ((unsigned)(a3 >> 32) == tag0)) break;
        __builtin_amdgcn_s_sleep(1);
      }
#pragma unroll
      for (int i = 0; i < 4; ++i) {
        int g = tid * 4 + i;
        int bb = (g & 15) >> 1, ub = (g >> 4) * 4 + (g & 1) * 2;
        u64 va = (i == 0) ? a0 : (i == 1) ? a1 : (i == 2) ? a2 : a3;
        *(unsigned int*)&v0s[bb][ub] = (unsigned int)va;
      }
    } else {
#pragma unroll
      for (int i = 0; i < 4; ++i) ((unsigned int*)v0s)[tid * 4 + i] = 0u;
    }
    __syncthreads();

    // ---- B0: layer0 partials ----
    if (p < 64) {
#pragma unroll
      for (int b = 0; b < 8; ++b) {
        uint4 q0 = *(const uint4*)&v0s[b][ks * 16];
        uint4 q1 = *(const uint4*)&v0s[b][ks * 16 + 8];
        float a = 0.f;
        a = fma8(q0, &w0reg[0], a);
        a = fma8(q1, &w0reg[8], a);
        part0[ks][b][r] = a;
      }
    }
    __syncthreads();

    // ---- C0 (lower half) || A1 poll h1(p-2) (upper half) ----
    if (tid < 128) {
      if (p < 64) {
        int b = tid >> 4, rr = tid & 15;
        float s = xz[p][b][rr];
#pragma unroll
        for (int k2 = 0; k2 < 16; ++k2) s += part0[k2][b][rr];
        zg0[b][rr] = s;
      }
    } else {
      int t2 = tid - 128;
      if (p >= 2) {
        const unsigned tag1 = (unsigned)(p - 1);
        const u64* s1p = &h1x[(size_t)(p - 2) * 1024 + t2 * 8];
        u64 e[8];
        for (;;) {
          bool ok = true;
#pragma unroll
          for (int i = 0; i < 8; ++i) {
            e[i] = __hip_atomic_load(&s1p[i], __ATOMIC_RELAXED, __HIP_MEMORY_SCOPE_AGENT);
            ok &= ((unsigned)(e[i] >> 32) == tag1);
          }
          if (ok) break;
          __builtin_amdgcn_s_sleep(1);
        }
#pragma unroll
        for (int i = 0; i < 8; ++i) {
          int g = t2 * 8 + i;
          int bb = (g & 15) >> 1, ub = (g >> 4) * 4 + (g & 1) * 2;
          *(unsigned int*)&w1h[bb][ub] = (unsigned int)e[i];
        }
      } else {
#pragma unroll
        for (int i = 0; i < 8; ++i) ((unsigned int*)w1h)[t2 * 8 + i] = 0u;
      }
    }
    __syncthreads();

    // ---- D0: update c0, publish h0(p) EARLY ----
    if (tid < 32 && p < 64) {
      int b = tid >> 2, uu = tid & 3;
      float zi = zg0[b][uu], zf = zg0[b][4 + uu], zgv = zg0[b][8 + uu], zo = zg0[b][12 + uu];
      c0 = sigf(zf) * c0 + sigf(zi) * tanhf(zgv);
      float h = sigf(zo) * tanhf(c0);
      float hp = __shfl_xor(h, 1);
      if (!(uu & 1)) {
        unsigned int d = (unsigned int)f2bf(h) | ((unsigned int)f2bf(hp) << 16);
        u64 v = ((u64)(unsigned)(p + 1) << 32) | d;
        __hip_atomic_store(&h0x[(size_t)p * 1024 + blkid * 16 + b * 2 + (uu >> 1)], v,
                           __ATOMIC_RELAXED, __HIP_MEMORY_SCOPE_AGENT);
      }
    }

    // ---- B1: layer1 partials ----
    if (p >= 1) {
      const unsigned short* sp = (ks < 8) ? &v0s[0][ks * 32] : &w1h[0][(ks - 8) * 32];
#pragma unroll
      for (int b = 0; b < 8; ++b) {
        const uint4* qp = (const uint4*)(sp + b * 256);
        float a = 0.f;
        a = fma8(qp[0], &w1reg[0], a);
        a = fma8(qp[1], &w1reg[8], a);
        a = fma8(qp[2], &w1reg[16], a);
        a = fma8(qp[3], &w1reg[24], a);
        part1[ks][b][r] = a;
      }
    }
    __syncthreads();

    // ---- C1: reduce zg1 ----
    if (tid >= 128 && p >= 1) {
      int t2 = tid - 128, b = t2 >> 4, rr = t2 & 15;
      float s = bias1s[rr];
#pragma unroll
      for (int k2 = 0; k2 < 16; ++k2) s += part1[k2][b][rr];
      zg1[b][rr] = s;
    }
    __syncthreads();

    // ---- D1: update c1, write comb, publish h1(p-1) ----
    if (tid < 32 && p >= 1) {
      int b = tid >> 2, uu = tid & 3;
      float zi = zg1[b][uu], zf = zg1[b][4 + uu], zgv = zg1[b][8 + uu], zo = zg1[b][12 + uu];
      c1 = sigf(zf) * c1 + sigf(zi) * tanhf(zgv);
      float h = sigf(zo) * tanhf(c1);
      comb[(size_t)(b * 64 + (p - 1)) * 576 + u0 + uu] = h;
      float hp = __shfl_xor(h, 1);
      if (!(uu & 1)) {
        unsigned int d = (unsigned int)f2bf(h) | ((unsigned int)f2bf(hp) << 16);
        u64 v = ((u64)(unsigned)p << 32) | d;
        __hip_atomic_store(&h1x[(size_t)(p - 1) * 1024 + blkid * 16 + b * 2 + (uu >> 1)], v,
                           __ATOMIC_RELAXED, __HIP_MEMORY_SCOPE_AGENT);
      }
    }
  }
}

// ---------- launcher ----------
extern "C" void kernel_launch(void* const* d_in, const int* in_sizes, int n_in,
                              void* d_out, int out_size, void* d_ws, size_t ws_size,
                              hipStream_t stream) {
  const float* fmap  = (const float*)d_in[0];
  const float* cond  = (const float*)d_in[1];
  const float* iseq  = (const float*)d_in[2];
  const float* steps = (const float*)d_in[3];
  const float* cw1 = (const float*)d_in[4];  const float* cb1 = (const float*)d_in[5];
  const float* g1  = (const float*)d_in[6];  const float* be1 = (const float*)d_in[7];
  const float* cw2 = (const float*)d_in[8];  const float* cb2 = (const float*)d_in[9];
  const float* g2  = (const float*)d_in[10]; const float* be2 = (const float*)d_in[11];
  const float* cw3 = (const float*)d_in[12]; const float* cb3 = (const float*)d_in[13];
  const float* g3  = (const float*)d_in[14]; const float* be3 = (const float*)d_in[15];
  const float* cw4 = (const float*)d_in[16]; const float* cb4 = (const float*)d_in[17];
  const float* g4  = (const float*)d_in[18]; const float* be4 = (const float*)d_in[19];
  const float* fw1 = (const float*)d_in[20]; const float* fb1 = (const float*)d_in[21];
  const float* fw2 = (const float*)d_in[22]; const float* fb2 = (const float*)d_in[23];
  const float* ew1 = (const float*)d_in[24]; const float* eb1 = (const float*)d_in[25];
  const float* ew2 = (const float*)d_in[26]; const float* eb2 = (const float*)d_in[27];
  const float* mw  = (const float*)d_in[28]; const float* mb  = (const float*)d_in[29];
  const float* w_ih0 = (const float*)d_in[30]; const float* w_hh0 = (const float*)d_in[31];
  const float* b_ih0 = (const float*)d_in[32]; const float* b_hh0 = (const float*)d_in[33];
  const float* w_ih1 = (const float*)d_in[34]; const float* w_hh1 = (const float*)d_in[35];
  const float* b_ih1 = (const float*)d_in[36]; const float* b_hh1 = (const float*)d_in[37];
  const float* xw1 = (const float*)d_in[38]; const float* xb1 = (const float*)d_in[39];
  const float* xw2 = (const float*)d_in[40]; const float* xb2 = (const float*)d_in[41];
  const float* ow  = (const float*)d_in[42]; const float* ob  = (const float*)d_in[43];

  float* ws = (float*)d_ws;
  unsigned short* y1bf  = (unsigned short*)ws;                 // [512][64][64][16]
  unsigned short* y2bf  = (unsigned short*)(ws + 16777216);    // [512][32][32][32]
  unsigned short* y3bf  = (unsigned short*)(ws + 25165824);    // [512][16][16][64]
  unsigned short* y4pre = (unsigned short*)(ws + 29360128);    // [512][8][8][128]
  unsigned short* y4bn  = (unsigned short*)(ws + 31457280);
  unsigned short* fw1bf = (unsigned short*)(ws + 33554432);    // permuted
  size_t base = 35651584;
  float* part  = ws + base; base += 131072;                    // 512 blocks x 2C (C<=128)
  float* ss1   = ws + base; base += 32;
  float* ss2   = ws + base; base += 64;
  float* ss3   = ws + base; base += 128;
  float* ss4   = ws + base; base += 256;
  float* f1    = ws + base; base += 262144;
  float* enh   = ws + base; base += 3072;
  float* ceh   = ws + base; base += 65536;
  u64*   h0x   = (u64*)(ws + base); base += 131072;
  u64*   h1x   = (u64*)(ws + base); base += 131072;
  float* comb  = ws + base; base += 294912;
  float* cx1   = ws + base; base += 65536;
  float* cx2   = ws + base; base += 32768;
  unsigned short* wt1 = (unsigned short*)(ws + base); base += 768;
  unsigned short* wt2 = (unsigned short*)(ws + base); base += 2304;
  unsigned short* wt3 = (unsigned short*)(ws + base); base += 9216;
  unsigned short* wt4 = (unsigned short*)(ws + base); base += 36864;

  // --- prep ---
  prep_wt<<<384, TPB, 0, stream>>>(cw1, cw2, cw3, cw4, wt1, wt2, wt3, wt4);
  permute_fw1<<<512, TPB, 0, stream>>>(fw1, fw1bf);

  // --- encoder convs (channel-last bf16) ---
  conv1_tap<<<4096, TPB, 0, stream>>>(fmap, iseq, wt1, cb1, y1bf);
  stats_cl2<<<STAT_NB, TPB, 0, stream>>>(y1bf, part, 16, 4194304);
  stats_final2<<<16, TPB, 0, stream>>>(part, g1, be1, ss1, 1.f / 2097152.f, 16);
  conv_tap<16, 32, 1, 64, 32><<<8192, TPB, 0, stream>>>(y1bf, ss1, wt2, cb2, y2bf);
  stats_cl2<<<STAT_NB, TPB, 0, stream>>>(y2bf, part, 32, 2097152);
  stats_final2<<<32, TPB, 0, stream>>>(part, g2, be2, ss2, 1.f / 524288.f, 32);
  conv_tap<32, 64, 1, 32, 16><<<2048, TPB, 0, stream>>>(y2bf, ss2, wt3, cb3, y3bf);
  stats_cl2<<<STAT_NB, TPB, 0, stream>>>(y3bf, part, 64, 1048576);
  stats_final2<<<64, TPB, 0, stream>>>(part, g3, be3, ss3, 1.f / 131072.f, 64);
  conv_tap<64, 32, 4, 16, 8><<<2048, TPB, 0, stream>>>(y3bf, ss3, wt4, cb4, y4pre);
  stats_cl2<<<STAT_NB, TPB, 0, stream>>>(y4pre, part, 128, 524288);
  stats_final2<<<128, TPB, 0, stream>>>(part, g4, be4, ss4, 1.f / 32768.f, 128);
  bnrelu_cl<<<2048, TPB, 0, stream>>>(y4pre, ss4, y4bn);

  // --- LSTM ---
  hipMemsetAsync(h0x, 0, 2 * 64 * 1024 * sizeof(u64), stream);
  lstm_kernel<<<NLB, TPB, 0, stream>>>(iseq, mw, mb,
                                       w_ih0, w_hh0, b_ih0, b_hh0,
                                       w_ih1, w_hh1, b_ih1, b_hh1,
                                       h0x, h1x, comb);

  // --- map-feature MLP (mapf written straight into comb cols 256..511) ---
  fc1_mfma<<<dim3(8, 8), TPB, 0, stream>>>(y4bn, fw1bf, fb1, f1);
  gemm_m64<<<dim3(4, 8), TPB, 0, stream>>>(f1, fw2, fb2, comb, 256, 512, 0, 576, 256);

  // --- condition encoder (condf -> comb cols 512..575) ---
  build_enh_kernel<<<12, TPB, 0, stream>>>(cond, steps, enh);
  gemm_m64<<<dim3(2, 8), TPB, 0, stream>>>(enh, ew1, eb1, ceh, 128, 6, 1, 128, 0);
  gemm_m64<<<dim3(1, 8), TPB, 0, stream>>>(ceh, ew2, eb2, comb, 64, 128, 0, 576, 512);

  // --- head ---
  gemm_m64<<<dim3(2, 8), TPB, 0, stream>>>(comb, xw1, xb1, cx1, 128, 576, 1, 128, 0);
  gemm_m64<<<dim3(1, 8), TPB, 0, stream>>>(cx1, xw2, xb2, cx2, 64, 128, 1, 64, 0);
  gemm_m64<<<dim3(1, 8), TPB, 0, stream>>>(cx2, ow, ob, (float*)d_out, 2, 64, 0, 2, 0);
}

// Round 9
// 670.046 us; speedup vs baseline: 2.4727x; 1.0053x over previous
//
#include <hip/hip_runtime.h>

#define TPB 256
#define NLB 64   // LSTM blocks

typedef float f32x4 __attribute__((ext_vector_type(4)));
typedef short bf16x8 __attribute__((ext_vector_type(8)));
typedef unsigned long long u64;

// ---------- helpers ----------
__device__ __forceinline__ float bf2f(unsigned short u) {
  union { unsigned int i; float f; } x; x.i = ((unsigned int)u) << 16; return x.f;
}
__device__ __forceinline__ unsigned short f2bf(float v) {
  union { float f; unsigned int i; } x; x.f = v;
  unsigned int r = (x.i + 0x7fffu + ((x.i >> 16) & 1u)) >> 16;
  return (unsigned short)r;
}
__device__ __forceinline__ float sigf(float x) { return 1.f / (1.f + __expf(-x)); }
__device__ __forceinline__ bf16x8 lda_bf8(const unsigned short* p) {
  union { uint4 u; bf16x8 v; } t; t.u = *(const uint4*)p; return t.v;
}
__device__ __forceinline__ bf16x8 frag_of(const unsigned int* w) {
  union { unsigned int u[4]; bf16x8 v; } t;
  t.u[0] = w[0]; t.u[1] = w[1]; t.u[2] = w[2]; t.u[3] = w[3]; return t.v;
}

// ================= conv1: crop patch staged once (bf16 channel-last), tap-shifted MFMA =================
// grid 4096 = 512 crops x 8 row-groups. out channel-last [n][64][64][16].
__global__ __launch_bounds__(TPB, 2) void conv1_tap(
    const float* __restrict__ fmap, const float* __restrict__ iseq,
    const unsigned short* __restrict__ wT,   // [16][96] bf16, k=tap*8+ic (zero pad)
    const float* __restrict__ bias,
    unsigned short* __restrict__ out) {
  __shared__ __align__(16) unsigned short patch[17][132][8];
  __shared__ unsigned short Bsm[16][104];
  __shared__ float bs[16];
  const int tid = threadIdx.x;
  const int n = blockIdx.x >> 3, R0 = (blockIdx.x & 7) << 3;
  const int y = (int)iseq[n * 2], x = (int)iseq[n * 2 + 1];
  const int bimg = n >> 6;

  for (int e = tid; e < 1536; e += TPB) Bsm[e / 96][e % 96] = wT[e];
  if (tid < 16) bs[tid] = bias[tid];
  for (int e = tid; e < 17 * 132; e += TPB)
    *(uint4*)&patch[e / 132][e % 132][0] = uint4{0u, 0u, 0u, 0u};
  __syncthreads();
  for (int e = tid; e < 3 * 17 * 132; e += TPB) {
    int ic = e / 2244, rem = e % 2244, l = rem / 132, c = rem % 132;
    int i = 2 * R0 - 1 + l, j = c - 1;
    float v = 0.f;
    if ((unsigned)i < 128u && (unsigned)j < 128u) {
      int r = y + i - 64, cc = x + j - 64;
      if ((unsigned)r < 1024u && (unsigned)cc < 1024u)
        v = fmap[(((size_t)bimg * 3 + ic) << 20) + ((size_t)r << 10) + cc];
    }
    patch[l][c][ic] = f2bf(v);
  }
  __syncthreads();

  const int w = tid >> 6, lane = tid & 63, fr = lane & 15, kg = lane >> 4;
  f32x4 acc[8];
#pragma unroll
  for (int m = 0; m < 8; ++m) acc[m] = {0.f, 0.f, 0.f, 0.f};

#pragma unroll
  for (int ch = 0; ch < 3; ++ch) {
    int k8 = ch * 4 + kg;
    int ki = (k8 >= 9) ? 0 : ((k8 * 11) >> 5);
    int kj = (k8 >= 9) ? 0 : (k8 - 3 * ki);
    bf16x8 bfr = lda_bf8(&Bsm[fr][k8 * 8]);
#pragma unroll
    for (int m = 0; m < 8; ++m) {
      int p = w * 128 + m * 16 + fr;
      int pr = p >> 6, pc = p & 63;
      bf16x8 af = lda_bf8(&patch[2 * pr + ki][2 * pc + kj][0]);
      acc[m] = __builtin_amdgcn_mfma_f32_16x16x32_bf16(af, bfr, acc[m], 0, 0, 0);
    }
  }
  const int rg = lane >> 4;
  float bb = bs[fr];
#pragma unroll
  for (int m = 0; m < 8; ++m) {
#pragma unroll
    for (int r = 0; r < 4; ++r) {
      int p = w * 128 + m * 16 + rg * 4 + r;
      int pr = p >> 6, pc = p & 63;
      out[(((size_t)n * 64 + R0 + pr) * 64 + pc) * 16 + fr] = f2bf(acc[m][r] + bb);
    }
  }
}

// ================= tap-shifted MFMA conv, channel-last I/O (conv2/3/4) =================
template<int CIN, int COUT_BLK, int NSPLIT, int HIN, int HOUT>
__global__ __launch_bounds__(TPB, 2) void conv_tap(
    const unsigned short* __restrict__ inb,
    const float* __restrict__ ss,
    const unsigned short* __restrict__ wT,
    const float* __restrict__ bias,
    unsigned short* __restrict__ out) {
  constexpr int K = CIN * 9;
  constexpr int K8 = K / 8;
  constexpr int NCH = (K8 + 3) / 4;
  constexpr int KPAD = NCH * 32;
  constexpr int BS = KPAD + 8;
  constexpr int CINP = CIN + 8;
  constexpr int ICG_SH = (CIN == 16) ? 1 : (CIN == 32) ? 2 : 3;
  constexpr int TPR = HOUT / 8;
  constexpr int TILES = TPR * TPR;
  constexpr int NT = COUT_BLK / 16;
  constexpr int COUT_TOT = COUT_BLK * NSPLIT;

  __shared__ unsigned short patch[289 * CINP];
  __shared__ unsigned short Bsm[COUT_BLK * BS];
  __shared__ float ssl[CIN * 2];

  const int tid = threadIdx.x;
  const int bid = blockIdx.x;
  const int n = bid / (TILES * NSPLIT);
  const int rem = bid % (TILES * NSPLIT);
  const int tile = rem / NSPLIT;
  const int split = rem % NSPLIT;
  const int TR0 = (tile / TPR) * 8, TC0 = (tile % TPR) * 8;
  const int oc0 = split * COUT_BLK;

  for (int i = tid; i < CIN * 2; i += TPB) ssl[i] = ss[i];
  __syncthreads();

  for (int e = tid; e < 289 * (CIN / 8); e += TPB) {
    int icg = e % (CIN / 8), pix = e / (CIN / 8);
    int row = pix / 17, col = pix % 17;
    int ir = 2 * TR0 - 1 + row, jc = 2 * TC0 - 1 + col;
    uint4 o = {0u, 0u, 0u, 0u};
    if ((unsigned)ir < (unsigned)HIN && (unsigned)jc < (unsigned)HIN) {
      uint4 v = *(const uint4*)&inb[(((size_t)n * HIN + ir) * HIN + jc) * CIN + icg * 8];
      unsigned int d[4] = {v.x, v.y, v.z, v.w};
      unsigned int* op = (unsigned int*)&o;
#pragma unroll
      for (int t = 0; t < 4; ++t) {
        int c = icg * 8 + 2 * t;
        float a = fmaxf(fmaf(bf2f((unsigned short)(d[t] & 0xffff)), ssl[2 * c], ssl[2 * c + 1]), 0.f);
        float b = fmaxf(fmaf(bf2f((unsigned short)(d[t] >> 16)), ssl[2 * c + 2], ssl[2 * c + 3]), 0.f);
        op[t] = (unsigned int)f2bf(a) | ((unsigned int)f2bf(b) << 16);
      }
    }
    *(uint4*)&patch[pix * CINP + icg * 8] = o;
  }
  constexpr int B8 = COUT_BLK * (KPAD / 8);
  for (int e = tid; e < B8; e += TPB) {
    int oc = e / (KPAD / 8), k8i = e % (KPAD / 8);
    uint4 v = {0u, 0u, 0u, 0u};
    if (k8i * 8 < K) v = *(const uint4*)&wT[(size_t)(oc0 + oc) * K + k8i * 8];
    *(uint4*)&Bsm[oc * BS + k8i * 8] = v;
  }
  __syncthreads();

  const int wave = tid >> 6, lane = tid & 63;
  const int fr = lane & 15, kg = lane >> 4;
  const int p = wave * 16 + fr;
  const int pr = p >> 3, pc = p & 7;
  f32x4 acc[NT];
#pragma unroll
  for (int j = 0; j < NT; ++j) acc[j] = {0.f, 0.f, 0.f, 0.f};

#pragma unroll
  for (int ch = 0; ch < NCH; ++ch) {
    int k8 = ch * 4 + kg;
    int tap = k8 >> ICG_SH, icg = k8 & ((1 << ICG_SH) - 1);
    int ki = (tap * 11) >> 5;
    int kj = tap - 3 * ki;
    int addr = ((2 * pr + ki) * 17 + (2 * pc + kj)) * CINP + icg * 8;
    if (tap >= 9) addr = 0;
    bf16x8 af = lda_bf8(&patch[addr]);
#pragma unroll
    for (int j = 0; j < NT; ++j) {
      bf16x8 bfr = lda_bf8(&Bsm[(j * 16 + fr) * BS + ch * 32 + kg * 8]);
      acc[j] = __builtin_amdgcn_mfma_f32_16x16x32_bf16(af, bfr, acc[j], 0, 0, 0);
    }
  }
  const int rg = lane >> 4;
#pragma unroll
  for (int j = 0; j < NT; ++j) {
    int oc = oc0 + j * 16 + fr;
    float bb = bias[oc];
#pragma unroll
    for (int r = 0; r < 4; ++r) {
      int pp = wave * 16 + rg * 4 + r;
      int orow = TR0 + (pp >> 3), ocol = TC0 + (pp & 7);
      out[(((size_t)n * HOUT + orow) * HOUT + ocol) * COUT_TOT + oc] = f2bf(acc[j][r] + bb);
    }
  }
}

// ---------- weight transpose+cast prep (tap-major bf16) ----------
__global__ __launch_bounds__(TPB) void prep_wt(
    const float* __restrict__ w1, const float* __restrict__ w2,
    const float* __restrict__ w3, const float* __restrict__ w4,
    unsigned short* __restrict__ wt1, unsigned short* __restrict__ wt2,
    unsigned short* __restrict__ wt3, unsigned short* __restrict__ wt4) {
  int i = blockIdx.x * TPB + threadIdx.x;
  if (i < 1536) {
    int oc = i / 96, k = i % 96;
    int tap = k >> 3, ic = k & 7;
    float v = (tap < 9 && ic < 3) ? w1[(oc * 3 + ic) * 9 + tap] : 0.f;
    wt1[i] = f2bf(v);
  } else if (i < 6144) {
    int j = i - 1536;
    int oc = j / 144, k = j % 144;
    wt2[j] = f2bf(w2[(oc * 16 + (k & 15)) * 9 + (k >> 4)]);
  } else if (i < 24576) {
    int j = i - 6144;
    int oc = j / 288, k = j % 288;
    wt3[j] = f2bf(w3[(oc * 32 + (k & 31)) * 9 + (k >> 5)]);
  } else if (i < 98304) {
    int j = i - 24576;
    int oc = j / 576, k = j % 576;
    wt4[j] = f2bf(w4[(oc * 64 + (k & 63)) * 9 + (k >> 6)]);
  }
}

// ---------- fw1 permute+cast ----------
__global__ __launch_bounds__(TPB) void permute_fw1(const float* __restrict__ in,
    unsigned short* __restrict__ out) {
  __shared__ unsigned short l[128 * 66];
  int n = blockIdx.x;
  for (int e = threadIdx.x; e < 8192; e += TPB) {
    int c = e >> 6, pix = e & 63;
    l[c * 66 + pix] = f2bf(in[(size_t)n * 8192 + e]);
  }
  __syncthreads();
  for (int e = threadIdx.x; e < 8192; e += TPB) {
    int pix = e >> 7, c = e & 127;
    out[(size_t)n * 8192 + e] = l[c * 66 + pix];
  }
}

// ---------- BN statistics, channel-last, vectorized ----------
#define STAT_NB 512
__global__ __launch_bounds__(TPB) void stats_cl2(
    const unsigned short* __restrict__ y, float* __restrict__ part,
    int C, int total_u4) {
  const int tid = threadIdx.x, bid = blockIdx.x;
  const int NQ = C >> 3;
  float s[8], q[8];
#pragma unroll
  for (int j = 0; j < 8; ++j) { s[j] = 0.f; q[j] = 0.f; }
  for (int i = bid * TPB + tid; i < total_u4; i += STAT_NB * TPB) {
    uint4 v = ((const uint4*)y)[i];
    unsigned int d[4] = {v.x, v.y, v.z, v.w};
#pragma unroll
    for (int t = 0; t < 4; ++t) {
      float a = bf2f((unsigned short)(d[t] & 0xffff));
      float b = bf2f((unsigned short)(d[t] >> 16));
      s[2 * t] += a;     q[2 * t] = fmaf(a, a, q[2 * t]);
      s[2 * t + 1] += b; q[2 * t + 1] = fmaf(b, b, q[2 * t + 1]);
    }
  }
  __shared__ float rs[TPB][8];
  __shared__ float rq[TPB][8];
#pragma unroll
  for (int j = 0; j < 8; ++j) { rs[tid][j] = s[j]; rq[tid][j] = q[j]; }
  __syncthreads();
  for (int off = TPB / 2; off >= NQ; off >>= 1) {
    if (tid < off) {
#pragma unroll
      for (int j = 0; j < 8; ++j) { rs[tid][j] += rs[tid + off][j]; rq[tid][j] += rq[tid + off][j]; }
    }
    __syncthreads();
  }
  if (tid < NQ) {
#pragma unroll
    for (int j = 0; j < 8; ++j) {
      int c = tid * 8 + j;
      part[(size_t)bid * 2 * C + 2 * c] = rs[tid][j];
      part[(size_t)bid * 2 * C + 2 * c + 1] = rq[tid][j];
    }
  }
}

__global__ __launch_bounds__(TPB) void stats_final2(const float* __restrict__ part,
    const float* __restrict__ gamma, const float* __restrict__ beta,
    float* __restrict__ ss, float inv_count, int C) {
  int c = blockIdx.x, tid = threadIdx.x;
  float sum = part[(size_t)tid * 2 * C + 2 * c] + part[(size_t)(tid + 256) * 2 * C + 2 * c];
  float sq  = part[(size_t)tid * 2 * C + 2 * c + 1] + part[(size_t)(tid + 256) * 2 * C + 2 * c + 1];
  __shared__ float rs[TPB], rq[TPB];
  rs[tid] = sum; rq[tid] = sq;
  __syncthreads();
  for (int off = TPB / 2; off > 0; off >>= 1) {
    if (tid < off) { rs[tid] += rs[tid + off]; rq[tid] += rq[tid + off]; }
    __syncthreads();
  }
  if (tid == 0) {
    float mean = rs[0] * inv_count;
    float var  = rq[0] * inv_count - mean * mean;
    float rstd = rsqrtf(var + 1e-5f);
    float scl  = gamma[c] * rstd;
    ss[2 * c] = scl;
    ss[2 * c + 1] = beta[c] - mean * scl;
  }
}

// ---------- fc1: bf16 MFMA GEMM, M=N=512, K=8192, BN(ss4)+relu fused ----------
__device__ __forceinline__ uint4 bnpack(uint4 v, const float* sst) {
  unsigned int d[4] = {v.x, v.y, v.z, v.w};
  uint4 o; unsigned int* op = (unsigned int*)&o;
#pragma unroll
  for (int t = 0; t < 4; ++t) {
    float a = fmaxf(fmaf(bf2f((unsigned short)(d[t] & 0xffff)), sst[4 * t], sst[4 * t + 1]), 0.f);
    float b = fmaxf(fmaf(bf2f((unsigned short)(d[t] >> 16)), sst[4 * t + 2], sst[4 * t + 3]), 0.f);
    op[t] = (unsigned int)f2bf(a) | ((unsigned int)f2bf(b) << 16);
  }
  return o;
}

__global__ __launch_bounds__(TPB, 2) void fc1_mfma(
    const unsigned short* __restrict__ A, const unsigned short* __restrict__ W,
    const float* __restrict__ ss, const float* __restrict__ bias,
    float* __restrict__ out) {
  __shared__ unsigned short As[64][64];
  __shared__ unsigned short Bs[64][64];
  __shared__ float ssl[256];
  const int tid = threadIdx.x;
  const int lane = tid & 63, wave = tid >> 6;
  const int wr = (wave >> 1) * 32, wc = (wave & 1) * 32;
  const int bm = blockIdx.y * 64, bn = blockIdx.x * 64;
  f32x4 acc00 = {0.f, 0.f, 0.f, 0.f}, acc01 = acc00, acc10 = acc00, acc11 = acc00;
  const int r0 = tid >> 3, c0 = tid & 7;
  const int fr = lane & 15, kg = lane >> 4;
  for (int i = tid; i < 256; i += TPB) ssl[i] = ss[i];
  __syncthreads();
  for (int kt = 0; kt < 128; ++kt) {
    const int kb = kt * 64;
    uint4 av0 = *(const uint4*)&A[(size_t)(bm + r0) * 8192 + kb + c0 * 8];
    uint4 av1 = *(const uint4*)&A[(size_t)(bm + r0 + 32) * 8192 + kb + c0 * 8];
    uint4 bv0 = *(const uint4*)&W[(size_t)(bn + r0) * 8192 + kb + c0 * 8];
    uint4 bv1 = *(const uint4*)&W[(size_t)(bn + r0 + 32) * 8192 + kb + c0 * 8];
    const float* sst = &ssl[2 * ((kb + c0 * 8) & 127)];
    __syncthreads();
    av0 = bnpack(av0, sst);
    av1 = bnpack(av1, sst);
    *(uint4*)&As[r0][(c0 ^ (r0 & 7)) * 8] = av0;
    *(uint4*)&As[r0 + 32][(c0 ^ (r0 & 7)) * 8] = av1;
    *(uint4*)&Bs[r0][(c0 ^ (r0 & 7)) * 8] = bv0;
    *(uint4*)&Bs[r0 + 32][(c0 ^ (r0 & 7)) * 8] = bv1;
    __syncthreads();
#pragma unroll
    for (int ks = 0; ks < 2; ++ks) {
      int ch = ks * 4 + kg;
      int ra0 = wr + fr, ra1 = wr + 16 + fr;
      int rb0 = wc + fr, rb1 = wc + 16 + fr;
      bf16x8 a_0 = lda_bf8(&As[ra0][(ch ^ (ra0 & 7)) * 8]);
      bf16x8 a_1 = lda_bf8(&As[ra1][(ch ^ (ra1 & 7)) * 8]);
      bf16x8 b_0 = lda_bf8(&Bs[rb0][(ch ^ (rb0 & 7)) * 8]);
      bf16x8 b_1 = lda_bf8(&Bs[rb1][(ch ^ (rb1 & 7)) * 8]);
      acc00 = __builtin_amdgcn_mfma_f32_16x16x32_bf16(a_0, b_0, acc00, 0, 0, 0);
      acc01 = __builtin_amdgcn_mfma_f32_16x16x32_bf16(a_0, b_1, acc01, 0, 0, 0);
      acc10 = __builtin_amdgcn_mfma_f32_16x16x32_bf16(a_1, b_0, acc10, 0, 0, 0);
      acc11 = __builtin_amdgcn_mfma_f32_16x16x32_bf16(a_1, b_1, acc11, 0, 0, 0);
    }
  }
  const int rg = lane >> 4;
  int n0 = bn + wc + fr, n1 = n0 + 16;
  float bi0 = bias[n0], bi1 = bias[n1];
#pragma unroll
  for (int r = 0; r < 4; ++r) {
    int m0 = bm + wr + rg * 4 + r, m1 = m0 + 16;
    out[m0 * 512 + n0] = fmaxf(acc00[r] + bi0, 0.f);
    out[m0 * 512 + n1] = fmaxf(acc01[r] + bi1, 0.f);
    out[m1 * 512 + n0] = fmaxf(acc10[r] + bi0, 0.f);
    out[m1 * 512 + n1] = fmaxf(acc11[r] + bi1, 0.f);
  }
}

// ---------- small GEMM via MFMA with output stride/offset ----------
__global__ __launch_bounds__(TPB, 2) void gemm_m64(
    const float* __restrict__ A, const float* __restrict__ W,
    const float* __restrict__ bias, float* __restrict__ out,
    int N, int K, int relu, int ldo, int coff) {
  __shared__ unsigned short As[64 * 40];
  __shared__ unsigned short Bs[64 * 40];
  const int tid = threadIdx.x, lane = tid & 63, wave = tid >> 6;
  const int wr = (wave >> 1) * 32, wc = (wave & 1) * 32;
  const int bm = blockIdx.y * 64, bn = blockIdx.x * 64;
  const int fr = lane & 15, kg = lane >> 4;
  const int sr = tid >> 2, sc = (tid & 3) * 8;
  f32x4 a00 = {0.f, 0.f, 0.f, 0.f}, a01 = a00, a10 = a00, a11 = a00;
  int nch = (K + 31) >> 5;
  for (int ch = 0; ch < nch; ++ch) {
    int kb = ch * 32;
    __syncthreads();
    {
      unsigned short tmp[8];
#pragma unroll
      for (int j = 0; j < 8; ++j) {
        int k = kb + sc + j;
        tmp[j] = (k < K) ? f2bf(A[(size_t)(bm + sr) * K + k]) : (unsigned short)0;
      }
      *(uint4*)&As[sr * 40 + sc] = *(const uint4*)tmp;
      int wrow = bn + sr;
#pragma unroll
      for (int j = 0; j < 8; ++j) {
        int k = kb + sc + j;
        tmp[j] = (wrow < N && k < K) ? f2bf(W[(size_t)wrow * K + k]) : (unsigned short)0;
      }
      *(uint4*)&Bs[sr * 40 + sc] = *(const uint4*)tmp;
    }
    __syncthreads();
    bf16x8 af0 = lda_bf8(&As[(wr + fr) * 40 + kg * 8]);
    bf16x8 af1 = lda_bf8(&As[(wr + 16 + fr) * 40 + kg * 8]);
    bf16x8 bf0 = lda_bf8(&Bs[(wc + fr) * 40 + kg * 8]);
    bf16x8 bf1 = lda_bf8(&Bs[(wc + 16 + fr) * 40 + kg * 8]);
    a00 = __builtin_amdgcn_mfma_f32_16x16x32_bf16(af0, bf0, a00, 0, 0, 0);
    a01 = __builtin_amdgcn_mfma_f32_16x16x32_bf16(af0, bf1, a01, 0, 0, 0);
    a10 = __builtin_amdgcn_mfma_f32_16x16x32_bf16(af1, bf0, a10, 0, 0, 0);
    a11 = __builtin_amdgcn_mfma_f32_16x16x32_bf16(af1, bf1, a11, 0, 0, 0);
  }
  const int rg = lane >> 4;
  int n0 = bn + wc + fr, n1 = n0 + 16;
  float bi0 = (n0 < N) ? bias[n0] : 0.f;
  float bi1 = (n1 < N) ? bias[n1] : 0.f;
#pragma unroll
  for (int r = 0; r < 4; ++r) {
    int m0 = bm + wr + rg * 4 + r, m1 = m0 + 16;
    if (n0 < N) {
      float v = a00[r] + bi0; out[(size_t)m0 * ldo + coff + n0] = relu ? fmaxf(v, 0.f) : v;
      v = a10[r] + bi0;       out[(size_t)m1 * ldo + coff + n0] = relu ? fmaxf(v, 0.f) : v;
    }
    if (n1 < N) {
      float v = a01[r] + bi1; out[(size_t)m0 * ldo + coff + n1] = relu ? fmaxf(v, 0.f) : v;
      v = a11[r] + bi1;       out[(size_t)m1 * ldo + coff + n1] = relu ? fmaxf(v, 0.f) : v;
    }
  }
}

// ---------- builders ----------
__global__ __launch_bounds__(TPB) void build_enh_kernel(const float* __restrict__ cond,
    const float* __restrict__ steps, float* __restrict__ enh) {
  int i = blockIdx.x * TPB + threadIdx.x;
  if (i >= 512 * 6) return;
  int n = i / 6, k = i % 6;
  int b = n >> 6, s = n & 63;
  enh[i] = (k < 5) ? cond[b * 5 + k] : steps[b * 64 + s];
}

// ---------- LSTM: MFMA gate matmuls, register bf16 weight fragments, tagged exchange ----------
// wave0: layer0 (h0 @ W_hh0^T); wave1: layer1-ih (h0 @ W_ih1^T); wave2: layer1-hh (h1 @ W_hh1^T).
__global__ __launch_bounds__(TPB, 1) void lstm_kernel(
    const float* __restrict__ iseq,
    const float* __restrict__ mw, const float* __restrict__ mb,
    const float* __restrict__ w_ih0, const float* __restrict__ w_hh0,
    const float* __restrict__ b_ih0, const float* __restrict__ b_hh0,
    const float* __restrict__ w_ih1, const float* __restrict__ w_hh1,
    const float* __restrict__ b_ih1, const float* __restrict__ b_hh1,
    u64* __restrict__ h0x, u64* __restrict__ h1x,
    float* __restrict__ comb) {
  const int tid = threadIdx.x;
  const int blkid = blockIdx.x;
  const int u0 = blkid * 4;

  __shared__ float xz[64][8][16];                  // x-part (+bias0) of layer0 gates
  __shared__ __align__(16) char reg2[18944];       // overlay region
  __shared__ float bias1s[16];

  // prologue overlays
  float (*embc)[8][32] = (float (*)[8][32])reg2;             // 16KB
  float* mwmb = (float*)(reg2 + 16384);
  // main overlays: packed-bf16 h staging [16 rows][264] (rows 8..15 zero)
  unsigned short (*v0s)[264] = (unsigned short (*)[264])reg2;           // 8448B
  unsigned short (*w1h)[264] = (unsigned short (*)[264])(reg2 + 8448);  // 8448B
  float (*P0)[16]  = (float (*)[16])(reg2 + 16896);
  float (*P1a)[16] = (float (*)[16])(reg2 + 17408);
  float (*P1b)[16] = (float (*)[16])(reg2 + 17920);

  const int wv = tid >> 6, lane = tid & 63, fr = lane & 15, kg = lane >> 4;
  const int r = tid & 15, ks = tid >> 4;
  const int R  = (r >> 2) * 256 + u0 + (r & 3);
  const int Rf = (fr >> 2) * 256 + u0 + (fr & 3);

  // --- weight B-fragments (bf16, registers) ---
  unsigned int wfrag[8][4];
  {
    const float* wsrc = (wv == 0) ? w_hh0 : (wv == 1) ? w_ih1 : w_hh1;
#pragma unroll
    for (int ch = 0; ch < 8; ++ch)
#pragma unroll
      for (int d = 0; d < 4; ++d) {
        float lo = wsrc[(size_t)Rf * 256 + ch * 32 + kg * 8 + d * 2];
        float hi = wsrc[(size_t)Rf * 256 + ch * 32 + kg * 8 + d * 2 + 1];
        wfrag[ch][d] = (unsigned)f2bf(lo) | ((unsigned)f2bf(hi) << 16);
      }
  }
  float wtmp[32];
#pragma unroll
  for (int i = 0; i < 32; ++i) wtmp[i] = w_ih0[R * 32 + i];
  const float bias0r = b_ih0[R] + b_hh0[R];
  if (tid < 16) bias1s[tid] = b_ih1[R] + b_hh1[R];
  if (tid < 96) mwmb[tid] = (tid < 64) ? mw[tid] : mb[tid - 64];
  __syncthreads();

  // --- prologue: emb + x-part of layer0 gates ---
  for (int chunk = 0; chunk < 4; ++chunk) {
    if (tid < 128) {
      int pp = tid >> 3, b = tid & 7;
      int pg = chunk * 16 + pp;
      float s0 = iseq[(b * 64 + pg) * 2 + 0];
      float s1 = iseq[(b * 64 + pg) * 2 + 1];
      for (int k = 0; k < 32; ++k)
        embc[pp][b][k] = fmaxf(fmaf(mwmb[2 * k], s0, fmaf(mwmb[2 * k + 1], s1, mwmb[64 + k])), 0.f);
    }
    __syncthreads();
    {
      int pg = chunk * 16 + ks;
      for (int b = 0; b < 8; ++b) {
        float a = bias0r;
        const float* e = &embc[ks][b][0];
#pragma unroll
        for (int k = 0; k < 32; ++k) a = fmaf(wtmp[k], e[k], a);
        xz[pg][b][r] = a;
      }
    }
    __syncthreads();
  }

  // zero pad rows 8..15 of staging (A-operand rows beyond batch)
  for (int i = tid; i < 8 * 264; i += TPB) {
    v0s[8 + i / 264][i % 264] = 0;
    w1h[8 + i / 264][i % 264] = 0;
  }
  __syncthreads();

  float c0 = 0.f, c1 = 0.f;
  for (int p = 0; p <= 64; ++p) {
    // ---- A: split poll+stage (tid<128: h0(p-1) -> v0s; tid>=128: h1(p-2) -> w1h) ----
    if (tid < 128) {
      if (p >= 1) {
        const unsigned tag0 = (unsigned)p;
        const u64* s0p = &h0x[(size_t)(p - 1) * 1024 + tid * 8];
        u64 e[8];
        for (;;) {
          bool ok = true;
#pragma unroll
          for (int i = 0; i < 8; ++i) {
            e[i] = __hip_atomic_load(&s0p[i], __ATOMIC_RELAXED, __HIP_MEMORY_SCOPE_AGENT);
            ok &= ((unsigned)(e[i] >> 32) == tag0);
          }
          if (ok) break;
          __builtin_amdgcn_s_sleep(1);
        }
#pragma unroll
        for (int i = 0; i < 8; ++i) {
          int g = tid * 8 + i;
          int bb = (g >> 1) & 7, ub = (g >> 4) * 4 + (g & 1) * 2;
          *(unsigned int*)&v0s[bb][ub] = (unsigned int)e[i];
        }
      } else {
#pragma unroll
        for (int i = 0; i < 8; ++i) {
          int g = tid * 8 + i;
          int bb = (g >> 1) & 7, ub = (g >> 4) * 4 + (g & 1) * 2;
          *(unsigned int*)&v0s[bb][ub] = 0u;
        }
      }
    } else {
      int t2 = tid - 128;
      if (p >= 2) {
        const unsigned tag1 = (unsigned)(p - 1);
        const u64* s1p = &h1x[(size_t)(p - 2) * 1024 + t2 * 8];
        u64 e[8];
        for (;;) {
          bool ok = true;
#pragma unroll
          for (int i = 0; i < 8; ++i) {
            e[i] = __hip_atomic_load(&s1p[i], __ATOMIC_RELAXED, __HIP_MEMORY_SCOPE_AGENT);
            ok &= ((unsigned)(e[i] >> 32) == tag1);
          }
          if (ok) break;
          __builtin_amdgcn_s_sleep(1);
        }
#pragma unroll
        for (int i = 0; i < 8; ++i) {
          int g = t2 * 8 + i;
          int bb = (g >> 1) & 7, ub = (g >> 4) * 4 + (g & 1) * 2;
          *(unsigned int*)&w1h[bb][ub] = (unsigned int)e[i];
        }
      } else {
#pragma unroll
        for (int i = 0; i < 8; ++i) {
          int g = t2 * 8 + i;
          int bb = (g >> 1) & 7, ub = (g >> 4) * 4 + (g & 1) * 2;
          *(unsigned int*)&w1h[bb][ub] = 0u;
        }
      }
    }
    __syncthreads();

    // ---- B: gate matmuls via MFMA (one wave each) ----
    if (wv == 0) {
      if (p < 64) {
        f32x4 acc = {0.f, 0.f, 0.f, 0.f};
#pragma unroll
        for (int ch = 0; ch < 8; ++ch) {
          bf16x8 af = lda_bf8(&v0s[fr][ch * 32 + kg * 8]);
          acc = __builtin_amdgcn_mfma_f32_16x16x32_bf16(af, frag_of(wfrag[ch]), acc, 0, 0, 0);
        }
#pragma unroll
        for (int j = 0; j < 4; ++j) {
          int bb2 = (lane >> 4) * 4 + j;
          if (bb2 < 8) P0[bb2][fr] = acc[j];
        }
      }
    } else if (wv == 1) {
      if (p >= 1) {
        f32x4 acc = {0.f, 0.f, 0.f, 0.f};
#pragma unroll
        for (int ch = 0; ch < 8; ++ch) {
          bf16x8 af = lda_bf8(&v0s[fr][ch * 32 + kg * 8]);
          acc = __builtin_amdgcn_mfma_f32_16x16x32_bf16(af, frag_of(wfrag[ch]), acc, 0, 0, 0);
        }
#pragma unroll
        for (int j = 0; j < 4; ++j) {
          int bb2 = (lane >> 4) * 4 + j;
          if (bb2 < 8) P1a[bb2][fr] = acc[j];
        }
      }
    } else if (wv == 2) {
      if (p >= 1) {
        f32x4 acc = {0.f, 0.f, 0.f, 0.f};
#pragma unroll
        for (int ch = 0; ch < 8; ++ch) {
          bf16x8 af = lda_bf8(&w1h[fr][ch * 32 + kg * 8]);
          acc = __builtin_amdgcn_mfma_f32_16x16x32_bf16(af, frag_of(wfrag[ch]), acc, 0, 0, 0);
        }
#pragma unroll
        for (int j = 0; j < 4; ++j) {
          int bb2 = (lane >> 4) * 4 + j;
          if (bb2 < 8) P1b[bb2][fr] = acc[j];
        }
      }
    }
    __syncthreads();

    // ---- D0: layer0 update, publish h0(p) ----
    if (tid < 32 && p < 64) {
      int b = tid >> 2, uu = tid & 3;
      float zi = P0[b][uu]      + xz[p][b][uu];
      float zf = P0[b][4 + uu]  + xz[p][b][4 + uu];
      float zg = P0[b][8 + uu]  + xz[p][b][8 + uu];
      float zo = P0[b][12 + uu] + xz[p][b][12 + uu];
      c0 = sigf(zf) * c0 + sigf(zi) * tanhf(zg);
      float h = sigf(zo) * tanhf(c0);
      float hp = __shfl_xor(h, 1);
      if (!(uu & 1)) {
        unsigned int d = (unsigned int)f2bf(h) | ((unsigned int)f2bf(hp) << 16);
        u64 v = ((u64)(unsigned)(p + 1) << 32) | d;
        __hip_atomic_store(&h0x[(size_t)p * 1024 + blkid * 16 + b * 2 + (uu >> 1)], v,
                           __ATOMIC_RELAXED, __HIP_MEMORY_SCOPE_AGENT);
      }
    } else if (tid >= 32 && tid < 64 && p >= 1) {
      // ---- D1: layer1 update (step p-1), write comb, publish h1(p-1) ----
      int t2 = tid - 32, b = t2 >> 2, uu = t2 & 3;
      float zi = P1a[b][uu]      + P1b[b][uu]      + bias1s[uu];
      float zf = P1a[b][4 + uu]  + P1b[b][4 + uu]  + bias1s[4 + uu];
      float zg = P1a[b][8 + uu]  + P1b[b][8 + uu]  + bias1s[8 + uu];
      float zo = P1a[b][12 + uu] + P1b[b][12 + uu] + bias1s[12 + uu];
      c1 = sigf(zf) * c1 + sigf(zi) * tanhf(zg);
      float h = sigf(zo) * tanhf(c1);
      comb[(size_t)(b * 64 + (p - 1)) * 576 + u0 + uu] = h;
      float hp = __shfl_xor(h, 1);
      if (!(uu & 1)) {
        unsigned int d = (unsigned int)f2bf(h) | ((unsigned int)f2bf(hp) << 16);
        u64 v = ((u64)(unsigned)p << 32) | d;
        __hip_atomic_store(&h1x[(size_t)(p - 1) * 1024 + blkid * 16 + b * 2 + (uu >> 1)], v,
                           __ATOMIC_RELAXED, __HIP_MEMORY_SCOPE_AGENT);
      }
    }
  }
}

// ---------- launcher ----------
extern "C" void kernel_launch(void* const* d_in, const int* in_sizes, int n_in,
                              void* d_out, int out_size, void* d_ws, size_t ws_size,
                              hipStream_t stream) {
  const float* fmap  = (const float*)d_in[0];
  const float* cond  = (const float*)d_in[1];
  const float* iseq  = (const float*)d_in[2];
  const float* steps = (const float*)d_in[3];
  const float* cw1 = (const float*)d_in[4];  const float* cb1 = (const float*)d_in[5];
  const float* g1  = (const float*)d_in[6];  const float* be1 = (const float*)d_in[7];
  const float* cw2 = (const float*)d_in[8];  const float* cb2 = (const float*)d_in[9];
  const float* g2  = (const float*)d_in[10]; const float* be2 = (const float*)d_in[11];
  const float* cw3 = (const float*)d_in[12]; const float* cb3 = (const float*)d_in[13];
  const float* g3  = (const float*)d_in[14]; const float* be3 = (const float*)d_in[15];
  const float* cw4 = (const float*)d_in[16]; const float* cb4 = (const float*)d_in[17];
  const float* g4  = (const float*)d_in[18]; const float* be4 = (const float*)d_in[19];
  const float* fw1 = (const float*)d_in[20]; const float* fb1 = (const float*)d_in[21];
  const float* fw2 = (const float*)d_in[22]; const float* fb2 = (const float*)d_in[23];
  const float* ew1 = (const float*)d_in[24]; const float* eb1 = (const float*)d_in[25];
  const float* ew2 = (const float*)d_in[26]; const float* eb2 = (const float*)d_in[27];
  const float* mw  = (const float*)d_in[28]; const float* mb  = (const float*)d_in[29];
  const float* w_ih0 = (const float*)d_in[30]; const float* w_hh0 = (const float*)d_in[31];
  const float* b_ih0 = (const float*)d_in[32]; const float* b_hh0 = (const float*)d_in[33];
  const float* w_ih1 = (const float*)d_in[34]; const float* w_hh1 = (const float*)d_in[35];
  const float* b_ih1 = (const float*)d_in[36]; const float* b_hh1 = (const float*)d_in[37];
  const float* xw1 = (const float*)d_in[38]; const float* xb1 = (const float*)d_in[39];
  const float* xw2 = (const float*)d_in[40]; const float* xb2 = (const float*)d_in[41];
  const float* ow  = (const float*)d_in[42]; const float* ob  = (const float*)d_in[43];

  float* ws = (float*)d_ws;
  unsigned short* y1bf  = (unsigned short*)ws;                 // [512][64][64][16]
  unsigned short* y2bf  = (unsigned short*)(ws + 16777216);    // [512][32][32][32]
  unsigned short* y3bf  = (unsigned short*)(ws + 25165824);    // [512][16][16][64]
  unsigned short* y4pre = (unsigned short*)(ws + 29360128);    // [512][8][8][128]
  unsigned short* fw1bf = (unsigned short*)(ws + 33554432);    // permuted
  size_t base = 35651584;
  float* part  = ws + base; base += 131072;
  float* ss1   = ws + base; base += 32;
  float* ss2   = ws + base; base += 64;
  float* ss3   = ws + base; base += 128;
  float* ss4   = ws + base; base += 256;
  float* f1    = ws + base; base += 262144;
  float* enh   = ws + base; base += 3072;
  float* ceh   = ws + base; base += 65536;
  u64*   h0x   = (u64*)(ws + base); base += 131072;
  u64*   h1x   = (u64*)(ws + base); base += 131072;
  float* comb  = ws + base; base += 294912;
  float* cx1   = ws + base; base += 65536;
  float* cx2   = ws + base; base += 32768;
  unsigned short* wt1 = (unsigned short*)(ws + base); base += 768;
  unsigned short* wt2 = (unsigned short*)(ws + base); base += 2304;
  unsigned short* wt3 = (unsigned short*)(ws + base); base += 9216;
  unsigned short* wt4 = (unsigned short*)(ws + base); base += 36864;

  // --- prep ---
  prep_wt<<<384, TPB, 0, stream>>>(cw1, cw2, cw3, cw4, wt1, wt2, wt3, wt4);
  permute_fw1<<<512, TPB, 0, stream>>>(fw1, fw1bf);

  // --- encoder convs (channel-last bf16) ---
  conv1_tap<<<4096, TPB, 0, stream>>>(fmap, iseq, wt1, cb1, y1bf);
  stats_cl2<<<STAT_NB, TPB, 0, stream>>>(y1bf, part, 16, 4194304);
  stats_final2<<<16, TPB, 0, stream>>>(part, g1, be1, ss1, 1.f / 2097152.f, 16);
  conv_tap<16, 32, 1, 64, 32><<<8192, TPB, 0, stream>>>(y1bf, ss1, wt2, cb2, y2bf);
  stats_cl2<<<STAT_NB, TPB, 0, stream>>>(y2bf, part, 32, 2097152);
  stats_final2<<<32, TPB, 0, stream>>>(part, g2, be2, ss2, 1.f / 524288.f, 32);
  conv_tap<32, 64, 1, 32, 16><<<2048, TPB, 0, stream>>>(y2bf, ss2, wt3, cb3, y3bf);
  stats_cl2<<<STAT_NB, TPB, 0, stream>>>(y3bf, part, 64, 1048576);
  stats_final2<<<64, TPB, 0, stream>>>(part, g3, be3, ss3, 1.f / 131072.f, 64);
  conv_tap<64, 32, 4, 16, 8><<<2048, TPB, 0, stream>>>(y3bf, ss3, wt4, cb4, y4pre);
  stats_cl2<<<STAT_NB, TPB, 0, stream>>>(y4pre, part, 128, 524288);
  stats_final2<<<128, TPB, 0, stream>>>(part, g4, be4, ss4, 1.f / 32768.f, 128);

  // --- LSTM ---
  hipMemsetAsync(h0x, 0, 2 * 64 * 1024 * sizeof(u64), stream);
  lstm_kernel<<<NLB, TPB, 0, stream>>>(iseq, mw, mb,
                                       w_ih0, w_hh0, b_ih0, b_hh0,
                                       w_ih1, w_hh1, b_ih1, b_hh1,
                                       h0x, h1x, comb);

  // --- map-feature MLP (BN fused into fc1 staging; mapf -> comb cols 256..511) ---
  fc1_mfma<<<dim3(8, 8), TPB, 0, stream>>>(y4pre, fw1bf, ss4, fb1, f1);
  gemm_m64<<<dim3(4, 8), TPB, 0, stream>>>(f1, fw2, fb2, comb, 256, 512, 0, 576, 256);

  // --- condition encoder (condf -> comb cols 512..575) ---
  build_enh_kernel<<<12, TPB, 0, stream>>>(cond, steps, enh);
  gemm_m64<<<dim3(2, 8), TPB, 0, stream>>>(enh, ew1, eb1, ceh, 128, 6, 1, 128, 0);
  gemm_m64<<<dim3(1, 8), TPB, 0, stream>>>(ceh, ew2, eb2, comb, 64, 128, 0, 576, 512);

  // --- head ---
  gemm_m64<<<dim3(2, 8), TPB, 0, stream>>>(comb, xw1, xb1, cx1, 128, 576, 1, 128, 0);
  gemm_m64<<<dim3(1, 8), TPB, 0, stream>>>(cx1, xw2, xb2, cx2, 64, 128, 1, 64, 0);
  gemm_m64<<<dim3(1, 8), TPB, 0, stream>>>(cx2, ow, ob, (float*)d_out, 2, 64, 0, 2, 0);
}